// Round 1
// baseline (791.351 us; speedup 1.0000x reference)
//
#include <hip/hip_runtime.h>
#include <hip/hip_bf16.h>

#define T_STEPS 8
#define F_IN    128
#define H_GCN   32
#define H_CONV  64
#define H_LSTM  128

typedef __bf16 bf16x8 __attribute__((ext_vector_type(8)));
typedef float  f32x4  __attribute__((ext_vector_type(4)));

__device__ __forceinline__ float sigm(float x)   { return 1.f / (1.f + __expf(-x)); }
__device__ __forceinline__ float tanh_f(float x) { return 1.f - 2.f / (__expf(2.f * x) + 1.f); }

__device__ __forceinline__ bf16x8 load_bf8(const __hip_bfloat16* p) {
  int4 v = *reinterpret_cast<const int4*>(p);
  return __builtin_bit_cast(bf16x8, v);
}

// ---------------- K1: h[r][o] = x[r][:] @ gcn_W[:,o], r in [0, N*T) ----------------
__global__ __launch_bounds__(256) void k_transform(const float* __restrict__ x,
                                                   const float* __restrict__ W,
                                                   float* __restrict__ h)
{
  __shared__ float Ws[F_IN * H_GCN];   // [f][o] row-major, same as input
  __shared__ float xs[8][F_IN];
  int tid = threadIdx.x;
  for (int i = tid; i < F_IN * H_GCN; i += 256) Ws[i] = W[i];
  long r0 = (long)blockIdx.x * 8;
  int idx = tid * 4;
  float4 xv = *reinterpret_cast<const float4*>(x + r0 * F_IN + idx);
  int rl = idx >> 7, c0 = idx & 127;
  xs[rl][c0] = xv.x; xs[rl][c0 + 1] = xv.y; xs[rl][c0 + 2] = xv.z; xs[rl][c0 + 3] = xv.w;
  __syncthreads();
  int rr = tid >> 5, o = tid & 31;
  float acc = 0.f;
  #pragma unroll 8
  for (int f = 0; f < F_IN; f += 4) {
    float4 x4 = *reinterpret_cast<const float4*>(&xs[rr][f]);
    acc = fmaf(x4.x, Ws[(f + 0) * H_GCN + o], acc);
    acc = fmaf(x4.y, Ws[(f + 1) * H_GCN + o], acc);
    acc = fmaf(x4.z, Ws[(f + 2) * H_GCN + o], acc);
    acc = fmaf(x4.w, Ws[(f + 3) * H_GCN + o], acc);
  }
  h[(r0 + rr) * H_GCN + o] = acc;
}

// ---------------- K2: in-degree count over col (targets) ----------------
__global__ void k_deg(const int* __restrict__ col, float* __restrict__ deg, int E)
{
  int i = blockIdx.x * 256 + threadIdx.x;
  if (i < E) unsafeAtomicAdd(&deg[col[i]], 1.0f);
}

// ---------------- K3: dinv = rsqrt(deg + 1) in place ----------------
__global__ void k_dinv(float* __restrict__ deg, int N)
{
  int i = blockIdx.x * 256 + threadIdx.x;
  if (i < N) deg[i] = rsqrtf(deg[i] + 1.0f);
}

// ---------------- K4: scatter messages (atomics) ----------------
__global__ __launch_bounds__(256) void k_scatter(const int* __restrict__ ei,
                                                 const float* __restrict__ dinv,
                                                 const float* __restrict__ h,
                                                 float* __restrict__ agg, int E)
{
  int tid = threadIdx.x;
  long e0 = (long)blockIdx.x * 8;
  #pragma unroll
  for (int k = 0; k < 8; ++k) {
    long e = e0 + k;
    if (e >= E) return;
    int r = ei[e], c = ei[E + e];
    float nrm = dinv[r] * dinv[c];
    float v = h[(long)r * 256 + tid] * nrm;
    unsafeAtomicAdd(&agg[(long)c * 256 + tid], v);
  }
}

// ---------------- K5: g = relu(agg + h*dinv^2 + gcn_b), in place into agg ----------------
__global__ __launch_bounds__(256) void k_finalize(float* __restrict__ agg,
                                                  const float* __restrict__ h,
                                                  const float* __restrict__ dinv,
                                                  const float* __restrict__ b)
{
  long i = (long)blockIdx.x * 256 + threadIdx.x;
  int n = (int)(i >> 8);
  int cc = (int)(i & 31);
  float di = dinv[n];
  float v = agg[i] + h[i] * di * di + b[cc];
  agg[i] = fmaxf(v, 0.f);
}

// ---------------- K6: Conv1d(32->64, k=2) + relu, output seq[t][n][co] as bf16 ----------------
__global__ __launch_bounds__(256) void k_conv(const float* __restrict__ g,
                                              const float* __restrict__ Wc,
                                              const float* __restrict__ bc,
                                              __hip_bfloat16* __restrict__ seq, int N)
{
  __shared__ float Ws[64 * 65];       // [co][ci*2+k], padded
  __shared__ float gs[4][8][33];      // [node][t][ci], padded
  int tid = threadIdx.x;
  for (int i = tid; i < 64 * 64; i += 256) Ws[(i >> 6) * 65 + (i & 63)] = Wc[i];
  int nl = tid >> 6, co = tid & 63;
  long n = (long)blockIdx.x * 4 + nl;
  {
    float4 v = *reinterpret_cast<const float4*>(g + n * 256 + co * 4);
    int t = co >> 3, w = (co & 7) * 4;
    gs[nl][t][w] = v.x; gs[nl][t][w + 1] = v.y; gs[nl][t][w + 2] = v.z; gs[nl][t][w + 3] = v.w;
  }
  __syncthreads();
  float bias = bc[co];
  const float* wrow = &Ws[co * 65];
  #pragma unroll
  for (int t = 0; t < 7; ++t) {
    float acc = bias;
    #pragma unroll 8
    for (int ci = 0; ci < 32; ++ci) {
      acc = fmaf(gs[nl][t][ci],     wrow[ci * 2],     acc);
      acc = fmaf(gs[nl][t + 1][ci], wrow[ci * 2 + 1], acc);
    }
    seq[(long)t * N * 64 + n * 64 + co] = __float2bfloat16(fmaxf(acc, 0.f));
  }
}

// ---------------- K7: pack bf16 weights Wcat[512][192] = [W_ih | W_hh], bias sum ----------------
__global__ void k_prep(const float* __restrict__ Wih, const float* __restrict__ Whh,
                       const float* __restrict__ bih, const float* __restrict__ bhh,
                       __hip_bfloat16* __restrict__ Wcat, float* __restrict__ bias)
{
  int q = threadIdx.x;   // 512 threads
  for (int k = 0; k < 64; ++k)  Wcat[q * 192 + k]      = __float2bfloat16(Wih[q * 64 + k]);
  for (int k = 0; k < 128; ++k) Wcat[q * 192 + 64 + k] = __float2bfloat16(Whh[q * 128 + k]);
  bias[q] = bih[q] + bhh[q];
}

// ---------------- K8: one LSTM step, fused MFMA GEMM + gates ----------------
// Block: 256 threads = 4 waves; 32 rows/block; wave w owns h-columns [w*32, w*32+32)
// across all 4 gates (q = g*128 + w*32 + hf*16 + l15) -> gates are wave-local.
__global__ __launch_bounds__(256) void k_lstm(const __hip_bfloat16* __restrict__ seq_t, // [N][64]
                                              __hip_bfloat16* __restrict__ hbf,         // [N][128]
                                              float* __restrict__ cst,                  // [N][128]
                                              const __hip_bfloat16* __restrict__ Wcat,  // [512][192]
                                              const float* __restrict__ bias, int N)
{
  int tid  = threadIdx.x;
  int wave = tid >> 6;
  int lane = tid & 63;
  int l15  = lane & 15;
  int lhi  = lane >> 4;
  long n0  = (long)blockIdx.x * 32;

  f32x4 acc[2][4][2];
  #pragma unroll
  for (int mt = 0; mt < 2; ++mt)
    #pragma unroll
    for (int gg = 0; gg < 4; ++gg)
      #pragma unroll
      for (int hf = 0; hf < 2; ++hf)
        acc[mt][gg][hf] = (f32x4){0.f, 0.f, 0.f, 0.f};

  #pragma unroll
  for (int ks = 0; ks < 6; ++ks) {
    bf16x8 a[2];
    if (ks < 2) {
      int koff = ks * 32 + lhi * 8;
      a[0] = load_bf8(seq_t + (n0 +      l15) * 64 + koff);
      a[1] = load_bf8(seq_t + (n0 + 16 + l15) * 64 + koff);
    } else {
      int koff = (ks - 2) * 32 + lhi * 8;
      a[0] = load_bf8(hbf + (n0 +      l15) * 128 + koff);
      a[1] = load_bf8(hbf + (n0 + 16 + l15) * 128 + koff);
    }
    int kb = ks * 32 + lhi * 8;
    #pragma unroll
    for (int gg = 0; gg < 4; ++gg) {
      #pragma unroll
      for (int hf = 0; hf < 2; ++hf) {
        int q = gg * 128 + wave * 32 + hf * 16 + l15;
        bf16x8 b = load_bf8(Wcat + q * 192 + kb);
        acc[0][gg][hf] = __builtin_amdgcn_mfma_f32_16x16x32_bf16(a[0], b, acc[0][gg][hf], 0, 0, 0);
        acc[1][gg][hf] = __builtin_amdgcn_mfma_f32_16x16x32_bf16(a[1], b, acc[1][gg][hf], 0, 0, 0);
      }
    }
  }
  __syncthreads();   // all reads of hbf done before any wave overwrites it

  #pragma unroll
  for (int mt = 0; mt < 2; ++mt) {
    #pragma unroll
    for (int hf = 0; hf < 2; ++hf) {
      int hcol = wave * 32 + hf * 16 + l15;
      float bi = bias[hcol], bff = bias[128 + hcol], bg = bias[256 + hcol], bo = bias[384 + hcol];
      #pragma unroll
      for (int r = 0; r < 4; ++r) {
        long row = n0 + mt * 16 + lhi * 4 + r;  // C/D layout: row = (lane>>4)*4 + reg
        float zi = acc[mt][0][hf][r] + bi;
        float zf = acc[mt][1][hf][r] + bff;
        float zg = acc[mt][2][hf][r] + bg;
        float zo = acc[mt][3][hf][r] + bo;
        long ix = row * 128 + hcol;
        float cp = cst[ix];
        float cn = sigm(zf) * cp + sigm(zi) * tanh_f(zg);
        float hn = sigm(zo) * tanh_f(cn);
        cst[ix] = cn;
        hbf[ix] = __float2bfloat16(hn);
      }
    }
  }
}

// ---------------- K9: head fc1(relu) -> fc2(sigmoid) ----------------
__global__ __launch_bounds__(128) void k_head(const __hip_bfloat16* __restrict__ hT,
                                              const float* __restrict__ fc1W, const float* __restrict__ fc1b,
                                              const float* __restrict__ fc2W, const float* __restrict__ fc2b,
                                              float* __restrict__ out, int N)
{
  __shared__ float w1[64 * 129];
  __shared__ float w2[128 * 65];
  __shared__ float hrow[128];
  __shared__ float s1[64];
  int tid = threadIdx.x;
  for (int i = tid; i < 64 * 128; i += 128) w1[(i >> 7) * 129 + (i & 127)] = fc1W[i];
  for (int i = tid; i < 128 * 64; i += 128) w2[(i >> 6) * 65 + (i & 63)] = fc2W[i];
  __syncthreads();
  for (long n = blockIdx.x; n < N; n += gridDim.x) {
    hrow[tid] = __bfloat162float(hT[n * 128 + tid]);
    __syncthreads();
    if (tid < 64) {
      float acc = fc1b[tid];
      #pragma unroll 8
      for (int j = 0; j < 128; ++j) acc = fmaf(hrow[j], w1[tid * 129 + j], acc);
      s1[tid] = fmaxf(acc, 0.f);
    }
    __syncthreads();
    float acc = fc2b[tid];
    #pragma unroll 8
    for (int j = 0; j < 64; ++j) acc = fmaf(s1[j], w2[tid * 65 + j], acc);
    out[n * 128 + tid] = 1.f / (1.f + __expf(-acc));
    __syncthreads();
  }
}

extern "C" void kernel_launch(void* const* d_in, const int* in_sizes, int n_in,
                              void* d_out, int out_size, void* d_ws, size_t ws_size,
                              hipStream_t stream)
{
  const float* x     = (const float*)d_in[0];
  const int*   ei    = (const int*)d_in[1];
  const float* gcnW  = (const float*)d_in[2];
  const float* gcnb  = (const float*)d_in[3];
  const float* convW = (const float*)d_in[4];
  const float* convb = (const float*)d_in[5];
  const float* Wih   = (const float*)d_in[6];
  const float* Whh   = (const float*)d_in[7];
  const float* bih   = (const float*)d_in[8];
  const float* bhh   = (const float*)d_in[9];
  const float* fc1W  = (const float*)d_in[10];
  const float* fc1b  = (const float*)d_in[11];
  const float* fc2W  = (const float*)d_in[12];
  const float* fc2b  = (const float*)d_in[13];

  const int N = in_sizes[0] / (T_STEPS * F_IN);
  const int E = in_sizes[1] / 2;

  char* ws = (char*)d_ws;
  size_t off = 0;
  auto alloc = [&](size_t bytes) {
    void* p = ws + off;
    off = (off + bytes + 255) & ~(size_t)255;
    return p;
  };
  float* h    = (float*)alloc((size_t)N * 256 * 4);   // [N][T][32]; reused as seq after finalize
  float* agg  = (float*)alloc((size_t)N * 256 * 4);   // [N][T][32]; g in place
  float* deg  = (float*)alloc((size_t)N * 4);          // deg -> dinv in place
  __hip_bfloat16* Wcat = (__hip_bfloat16*)alloc(512 * 192 * 2);
  float* bias = (float*)alloc(512 * 4);
  __hip_bfloat16* hbf = (__hip_bfloat16*)alloc((size_t)N * 128 * 2);
  float* cst  = (float*)alloc((size_t)N * 128 * 4);
  __hip_bfloat16* seq = (__hip_bfloat16*)h;            // 7*N*64*2 = 17.9MB <= 20.5MB

  hipMemsetAsync(deg, 0, (size_t)N * 4, stream);
  hipMemsetAsync(agg, 0, (size_t)N * 256 * 4, stream);
  hipMemsetAsync(hbf, 0, (size_t)N * 128 * 2, stream);
  hipMemsetAsync(cst, 0, (size_t)N * 128 * 4, stream);

  k_prep<<<1, 512, 0, stream>>>(Wih, Whh, bih, bhh, Wcat, bias);
  k_transform<<<(N * T_STEPS) / 8, 256, 0, stream>>>(x, gcnW, h);
  k_deg<<<(E + 255) / 256, 256, 0, stream>>>(ei + E, deg, E);
  k_dinv<<<(N + 255) / 256, 256, 0, stream>>>(deg, N);
  k_scatter<<<(E + 7) / 8, 256, 0, stream>>>(ei, deg, h, agg, E);
  k_finalize<<<N, 256, 0, stream>>>(agg, h, deg, gcnb);
  k_conv<<<N / 4, 256, 0, stream>>>(agg, convW, convb, seq, N);
  for (int t = 0; t < 7; ++t)
    k_lstm<<<N / 32, 256, 0, stream>>>(seq + (size_t)t * N * 64, hbf, cst, Wcat, bias, N);
  k_head<<<2048, 128, 0, stream>>>(hbf, fc1W, fc1b, fc2W, fc2b, (float*)d_out, N);
}

// Round 2
// 604.409 us; speedup vs baseline: 1.3093x; 1.3093x over previous
//
#include <hip/hip_runtime.h>
#include <hip/hip_bf16.h>

#define T_STEPS 8
#define F_IN    128
#define H_GCN   32
#define H_CONV  64
#define H_LSTM  128

typedef __bf16 bf16x8 __attribute__((ext_vector_type(8)));
typedef float  f32x4  __attribute__((ext_vector_type(4)));

__device__ __forceinline__ float sigm(float x)   { return 1.f / (1.f + __expf(-x)); }
__device__ __forceinline__ float tanh_f(float x) { return 1.f - 2.f / (__expf(2.f * x) + 1.f); }

__device__ __forceinline__ bf16x8 load_bf8(const __hip_bfloat16* p) {
  int4 v = *reinterpret_cast<const int4*>(p);
  return __builtin_bit_cast(bf16x8, v);
}

// ---------------- K1: h[r][o] = x[r][:] @ gcn_W[:,o], r in [0, N*T) ----------------
__global__ __launch_bounds__(256) void k_transform(const float* __restrict__ x,
                                                   const float* __restrict__ W,
                                                   float* __restrict__ h)
{
  __shared__ float Ws[F_IN * H_GCN];   // [f][o] row-major
  __shared__ float xs[8][F_IN];
  int tid = threadIdx.x;
  for (int i = tid; i < F_IN * H_GCN; i += 256) Ws[i] = W[i];
  long r0 = (long)blockIdx.x * 8;
  int idx = tid * 4;
  float4 xv = *reinterpret_cast<const float4*>(x + r0 * F_IN + idx);
  int rl = idx >> 7, c0 = idx & 127;
  xs[rl][c0] = xv.x; xs[rl][c0 + 1] = xv.y; xs[rl][c0 + 2] = xv.z; xs[rl][c0 + 3] = xv.w;
  __syncthreads();
  int rr = tid >> 5, o = tid & 31;
  float acc = 0.f;
  #pragma unroll 8
  for (int f = 0; f < F_IN; f += 4) {
    float4 x4 = *reinterpret_cast<const float4*>(&xs[rr][f]);
    acc = fmaf(x4.x, Ws[(f + 0) * H_GCN + o], acc);
    acc = fmaf(x4.y, Ws[(f + 1) * H_GCN + o], acc);
    acc = fmaf(x4.z, Ws[(f + 2) * H_GCN + o], acc);
    acc = fmaf(x4.w, Ws[(f + 3) * H_GCN + o], acc);
  }
  h[(r0 + rr) * H_GCN + o] = acc;
}

// ---------------- K2: in-degree count (int) over col (targets) ----------------
__global__ void k_count(const int* __restrict__ col, int* __restrict__ cnt, int E)
{
  int i = blockIdx.x * 256 + threadIdx.x;
  if (i < E) atomicAdd(&cnt[col[i]], 1);
}

// ---------------- K3: single-block chunked scan -> row_ptr, cursor, dinv ----------------
__global__ __launch_bounds__(1024) void k_scan(const int* __restrict__ cnt,
                                               int* __restrict__ row_ptr,
                                               int* __restrict__ cursor,
                                               float* __restrict__ dinv, int N)
{
  __shared__ int s[1024];
  int tid = threadIdx.x;
  const int CH = (N + 1023) >> 10;
  int i0 = tid * CH;
  int sum = 0;
  for (int j = 0; j < CH; ++j) {
    int i = i0 + j;
    sum += (i < N) ? cnt[i] : 0;
  }
  s[tid] = sum;
  __syncthreads();
  #pragma unroll
  for (int off = 1; off < 1024; off <<= 1) {
    int t = (tid >= off) ? s[tid - off] : 0;
    __syncthreads();
    s[tid] += t;
    __syncthreads();
  }
  int run = (tid > 0) ? s[tid - 1] : 0;   // exclusive prefix of this thread's chunk
  for (int j = 0; j < CH; ++j) {
    int i = i0 + j;
    if (i < N) {
      int v = cnt[i];
      cursor[i] = run;
      dinv[i] = rsqrtf((float)v + 1.0f);
      run += v;
      row_ptr[i + 1] = run;
    }
  }
  if (tid == 0) row_ptr[0] = 0;
}

// ---------------- K4: fill adjacency (source list per target) ----------------
__global__ void k_fill(const int* __restrict__ ei, int* __restrict__ cursor,
                       int* __restrict__ adj, int E)
{
  int e = blockIdx.x * 256 + threadIdx.x;
  if (e < E) {
    int r = ei[e], c = ei[E + e];
    int pos = atomicAdd(&cursor[c], 1);
    adj[pos] = r;
  }
}

// ---------------- K5: fused gather + relu + Conv1d(32->64,k=2) + relu -> seq bf16 ----------------
// One block per target node. Thread tid owns column tid of the 256-wide h row
// (t = tid>>5, ci = tid&31).
__global__ __launch_bounds__(256) void k_gather_conv(
    const int* __restrict__ row_ptr, const int* __restrict__ adj,
    const float* __restrict__ dinv, const float* __restrict__ h,
    const float* __restrict__ gcnb,
    const float* __restrict__ Wc, const float* __restrict__ bc,
    __hip_bfloat16* __restrict__ seq, int N)
{
  __shared__ float Ws[64 * 65];   // transposed conv weights: [(ci*2+k)*65 + co]
  __shared__ float gs[8][33];     // [t][ci], padded
  __shared__ int   nbr[256];
  __shared__ float nbrd[256];
  int tid = threadIdx.x;
  int n = blockIdx.x;

  // load conv weights transposed (global read coalesced, LDS stride-65 write conflict-free)
  for (int i = tid; i < 64 * 64; i += 256) {
    int co = i >> 6, ci2 = i & 63;
    Ws[ci2 * 65 + co] = Wc[i];
  }

  int start = row_ptr[n], end = row_ptr[n + 1];
  float dn = dinv[n];
  float acc = h[(long)n * 256 + tid] * dn;   // self loop (dn applied once more at end)

  for (int base = start; base < end; base += 256) {
    int m = end - base; if (m > 256) m = 256;
    __syncthreads();
    if (tid < m) {
      int src = adj[base + tid];
      nbr[tid] = src;
      nbrd[tid] = dinv[src];
    }
    __syncthreads();
    for (int j = 0; j < m; ++j)
      acc = fmaf(h[(long)nbr[j] * 256 + tid], nbrd[j], acc);
  }

  float g = fmaxf(fmaf(acc, dn, gcnb[tid & 31]), 0.f);
  gs[tid >> 5][tid & 31] = g;
  __syncthreads();

  long n64 = (long)N * 64;
  #pragma unroll
  for (int rep = 0; rep < 2; ++rep) {
    int p = rep * 256 + tid;
    if (p < 448) {
      int t = p >> 6, co = p & 63;
      float o = bc[co];
      #pragma unroll
      for (int ci = 0; ci < 32; ++ci) {
        o = fmaf(gs[t][ci],     Ws[(ci * 2)     * 65 + co], o);
        o = fmaf(gs[t + 1][ci], Ws[(ci * 2 + 1) * 65 + co], o);
      }
      seq[(long)t * n64 + (long)n * 64 + co] = __float2bfloat16(fmaxf(o, 0.f));
    }
  }
}

// ---------------- K6: pack bf16 weights Wcat[512][192] = [W_ih | W_hh], bias sum ----------------
__global__ void k_prep(const float* __restrict__ Wih, const float* __restrict__ Whh,
                       const float* __restrict__ bih, const float* __restrict__ bhh,
                       __hip_bfloat16* __restrict__ Wcat, float* __restrict__ bias)
{
  int q = threadIdx.x;   // 512 threads
  for (int k = 0; k < 64; ++k)  Wcat[q * 192 + k]      = __float2bfloat16(Wih[q * 64 + k]);
  for (int k = 0; k < 128; ++k) Wcat[q * 192 + 64 + k] = __float2bfloat16(Whh[q * 128 + k]);
  bias[q] = bih[q] + bhh[q];
}

// ---------------- K7: one LSTM step, fused MFMA GEMM + gates ----------------
__global__ __launch_bounds__(256) void k_lstm(const __hip_bfloat16* __restrict__ seq_t, // [N][64]
                                              __hip_bfloat16* __restrict__ hbf,         // [N][128]
                                              float* __restrict__ cst,                  // [N][128]
                                              const __hip_bfloat16* __restrict__ Wcat,  // [512][192]
                                              const float* __restrict__ bias, int N)
{
  int tid  = threadIdx.x;
  int wave = tid >> 6;
  int lane = tid & 63;
  int l15  = lane & 15;
  int lhi  = lane >> 4;
  long n0  = (long)blockIdx.x * 32;

  f32x4 acc[2][4][2];
  #pragma unroll
  for (int mt = 0; mt < 2; ++mt)
    #pragma unroll
    for (int gg = 0; gg < 4; ++gg)
      #pragma unroll
      for (int hf = 0; hf < 2; ++hf)
        acc[mt][gg][hf] = (f32x4){0.f, 0.f, 0.f, 0.f};

  #pragma unroll
  for (int ks = 0; ks < 6; ++ks) {
    bf16x8 a[2];
    if (ks < 2) {
      int koff = ks * 32 + lhi * 8;
      a[0] = load_bf8(seq_t + (n0 +      l15) * 64 + koff);
      a[1] = load_bf8(seq_t + (n0 + 16 + l15) * 64 + koff);
    } else {
      int koff = (ks - 2) * 32 + lhi * 8;
      a[0] = load_bf8(hbf + (n0 +      l15) * 128 + koff);
      a[1] = load_bf8(hbf + (n0 + 16 + l15) * 128 + koff);
    }
    int kb = ks * 32 + lhi * 8;
    #pragma unroll
    for (int gg = 0; gg < 4; ++gg) {
      #pragma unroll
      for (int hf = 0; hf < 2; ++hf) {
        int q = gg * 128 + wave * 32 + hf * 16 + l15;
        bf16x8 b = load_bf8(Wcat + q * 192 + kb);
        acc[0][gg][hf] = __builtin_amdgcn_mfma_f32_16x16x32_bf16(a[0], b, acc[0][gg][hf], 0, 0, 0);
        acc[1][gg][hf] = __builtin_amdgcn_mfma_f32_16x16x32_bf16(a[1], b, acc[1][gg][hf], 0, 0, 0);
      }
    }
  }
  __syncthreads();   // all reads of hbf done before any wave overwrites it

  #pragma unroll
  for (int mt = 0; mt < 2; ++mt) {
    #pragma unroll
    for (int hf = 0; hf < 2; ++hf) {
      int hcol = wave * 32 + hf * 16 + l15;
      float bi = bias[hcol], bff = bias[128 + hcol], bg = bias[256 + hcol], bo = bias[384 + hcol];
      #pragma unroll
      for (int r = 0; r < 4; ++r) {
        long row = n0 + mt * 16 + lhi * 4 + r;
        float zi = acc[mt][0][hf][r] + bi;
        float zf = acc[mt][1][hf][r] + bff;
        float zg = acc[mt][2][hf][r] + bg;
        float zo = acc[mt][3][hf][r] + bo;
        long ix = row * 128 + hcol;
        float cp = cst[ix];
        float cn = sigm(zf) * cp + sigm(zi) * tanh_f(zg);
        float hn = sigm(zo) * tanh_f(cn);
        cst[ix] = cn;
        hbf[ix] = __float2bfloat16(hn);
      }
    }
  }
}

// ---------------- K8: head fc1(relu) -> fc2(sigmoid) ----------------
__global__ __launch_bounds__(128) void k_head(const __hip_bfloat16* __restrict__ hT,
                                              const float* __restrict__ fc1W, const float* __restrict__ fc1b,
                                              const float* __restrict__ fc2W, const float* __restrict__ fc2b,
                                              float* __restrict__ out, int N)
{
  __shared__ float w1[64 * 129];
  __shared__ float w2[128 * 65];
  __shared__ float hrow[128];
  __shared__ float s1[64];
  int tid = threadIdx.x;
  for (int i = tid; i < 64 * 128; i += 128) w1[(i >> 7) * 129 + (i & 127)] = fc1W[i];
  for (int i = tid; i < 128 * 64; i += 128) w2[(i >> 6) * 65 + (i & 63)] = fc2W[i];
  __syncthreads();
  for (long n = blockIdx.x; n < N; n += gridDim.x) {
    hrow[tid] = __bfloat162float(hT[n * 128 + tid]);
    __syncthreads();
    if (tid < 64) {
      float acc = fc1b[tid];
      #pragma unroll 8
      for (int j = 0; j < 128; ++j) acc = fmaf(hrow[j], w1[tid * 129 + j], acc);
      s1[tid] = fmaxf(acc, 0.f);
    }
    __syncthreads();
    float acc = fc2b[tid];
    #pragma unroll 8
    for (int j = 0; j < 64; ++j) acc = fmaf(s1[j], w2[tid * 65 + j], acc);
    out[n * 128 + tid] = 1.f / (1.f + __expf(-acc));
    __syncthreads();
  }
}

extern "C" void kernel_launch(void* const* d_in, const int* in_sizes, int n_in,
                              void* d_out, int out_size, void* d_ws, size_t ws_size,
                              hipStream_t stream)
{
  const float* x     = (const float*)d_in[0];
  const int*   ei    = (const int*)d_in[1];
  const float* gcnW  = (const float*)d_in[2];
  const float* gcnb  = (const float*)d_in[3];
  const float* convW = (const float*)d_in[4];
  const float* convb = (const float*)d_in[5];
  const float* Wih   = (const float*)d_in[6];
  const float* Whh   = (const float*)d_in[7];
  const float* bih   = (const float*)d_in[8];
  const float* bhh   = (const float*)d_in[9];
  const float* fc1W  = (const float*)d_in[10];
  const float* fc1b  = (const float*)d_in[11];
  const float* fc2W  = (const float*)d_in[12];
  const float* fc2b  = (const float*)d_in[13];

  const int N = in_sizes[0] / (T_STEPS * F_IN);
  const int E = in_sizes[1] / 2;

  char* ws = (char*)d_ws;
  size_t off = 0;
  auto alloc = [&](size_t bytes) {
    void* p = ws + off;
    off = (off + bytes + 255) & ~(size_t)255;
    return p;
  };
  float* h    = (float*)alloc((size_t)N * 256 * 4);        // [N][T][32]
  __hip_bfloat16* seq = (__hip_bfloat16*)alloc((size_t)7 * N * 64 * 2); // [7][N][64]
  int* cnt     = (int*)alloc((size_t)N * 4);
  int* row_ptr = (int*)alloc((size_t)(N + 1) * 4);
  int* cursor  = (int*)alloc((size_t)N * 4);
  float* dinv  = (float*)alloc((size_t)N * 4);
  int* adj     = (int*)alloc((size_t)E * 4);
  __hip_bfloat16* Wcat = (__hip_bfloat16*)alloc(512 * 192 * 2);
  float* bias = (float*)alloc(512 * 4);
  __hip_bfloat16* hbf = (__hip_bfloat16*)alloc((size_t)N * 128 * 2);
  float* cst  = (float*)alloc((size_t)N * 128 * 4);

  hipMemsetAsync(cnt, 0, (size_t)N * 4, stream);
  hipMemsetAsync(hbf, 0, (size_t)N * 128 * 2, stream);
  hipMemsetAsync(cst, 0, (size_t)N * 128 * 4, stream);

  k_prep<<<1, 512, 0, stream>>>(Wih, Whh, bih, bhh, Wcat, bias);
  k_transform<<<(N * T_STEPS) / 8, 256, 0, stream>>>(x, gcnW, h);
  k_count<<<(E + 255) / 256, 256, 0, stream>>>(ei + E, cnt, E);
  k_scan<<<1, 1024, 0, stream>>>(cnt, row_ptr, cursor, dinv, N);
  k_fill<<<(E + 255) / 256, 256, 0, stream>>>(ei, cursor, adj, E);
  k_gather_conv<<<N, 256, 0, stream>>>(row_ptr, adj, dinv, h, gcnb, convW, convb, seq, N);
  for (int t = 0; t < 7; ++t)
    k_lstm<<<N / 32, 256, 0, stream>>>(seq + (size_t)t * N * 64, hbf, cst, Wcat, bias, N);
  k_head<<<2048, 128, 0, stream>>>(hbf, fc1W, fc1b, fc2W, fc2b, (float*)d_out, N);
}

// Round 3
// 422.765 us; speedup vs baseline: 1.8718x; 1.4297x over previous
//
#include <hip/hip_runtime.h>
#include <hip/hip_bf16.h>

#define T_STEPS 8
#define F_IN    128
#define H_GCN   32
#define H_CONV  64
#define H_LSTM  128

typedef __bf16 bf16x8 __attribute__((ext_vector_type(8)));
typedef float  f32x4  __attribute__((ext_vector_type(4)));

__device__ __forceinline__ float sigm(float x)   { return 1.f / (1.f + __expf(-x)); }
__device__ __forceinline__ float tanh_f(float x) { return 1.f - 2.f / (__expf(2.f * x) + 1.f); }
__device__ __forceinline__ float cvbf(__hip_bfloat16 v) { return __bfloat162float(v); }

__device__ __forceinline__ bf16x8 load_bf8(const __hip_bfloat16* p) {
  int4 v = *reinterpret_cast<const int4*>(p);
  return __builtin_bit_cast(bf16x8, v);
}

// ---------------- K1: h[r][o] = x[r][:] @ gcn_W[:,o], bf16 out ----------------
__global__ __launch_bounds__(256) void k_transform(const float* __restrict__ x,
                                                   const float* __restrict__ W,
                                                   __hip_bfloat16* __restrict__ h)
{
  __shared__ float Ws[F_IN * H_GCN];
  __shared__ float xs[8][F_IN];
  int tid = threadIdx.x;
  for (int i = tid; i < F_IN * H_GCN; i += 256) Ws[i] = W[i];
  long r0 = (long)blockIdx.x * 8;
  int idx = tid * 4;
  float4 xv = *reinterpret_cast<const float4*>(x + r0 * F_IN + idx);
  int rl = idx >> 7, c0 = idx & 127;
  xs[rl][c0] = xv.x; xs[rl][c0 + 1] = xv.y; xs[rl][c0 + 2] = xv.z; xs[rl][c0 + 3] = xv.w;
  __syncthreads();
  int rr = tid >> 5, o = tid & 31;
  float acc = 0.f;
  #pragma unroll 8
  for (int f = 0; f < F_IN; f += 4) {
    float4 x4 = *reinterpret_cast<const float4*>(&xs[rr][f]);
    acc = fmaf(x4.x, Ws[(f + 0) * H_GCN + o], acc);
    acc = fmaf(x4.y, Ws[(f + 1) * H_GCN + o], acc);
    acc = fmaf(x4.z, Ws[(f + 2) * H_GCN + o], acc);
    acc = fmaf(x4.w, Ws[(f + 3) * H_GCN + o], acc);
  }
  h[(r0 + rr) * H_GCN + o] = __float2bfloat16(acc);
}

// ---------------- K2: in-degree count ----------------
__global__ void k_count(const int* __restrict__ col, int* __restrict__ cnt, int E)
{
  int i = blockIdx.x * 256 + threadIdx.x;
  if (i < E) atomicAdd(&cnt[col[i]], 1);
}

// ---------------- K3: single-block chunked scan -> row_ptr, cursor, dinv ----------------
__global__ __launch_bounds__(1024) void k_scan(const int* __restrict__ cnt,
                                               int* __restrict__ row_ptr,
                                               int* __restrict__ cursor,
                                               float* __restrict__ dinv, int N)
{
  __shared__ int s[1024];
  int tid = threadIdx.x;
  const int CH = (N + 1023) >> 10;
  int i0 = tid * CH;
  int sum = 0;
  for (int j = 0; j < CH; ++j) {
    int i = i0 + j;
    sum += (i < N) ? cnt[i] : 0;
  }
  s[tid] = sum;
  __syncthreads();
  #pragma unroll
  for (int off = 1; off < 1024; off <<= 1) {
    int t = (tid >= off) ? s[tid - off] : 0;
    __syncthreads();
    s[tid] += t;
    __syncthreads();
  }
  int run = (tid > 0) ? s[tid - 1] : 0;
  for (int j = 0; j < CH; ++j) {
    int i = i0 + j;
    if (i < N) {
      int v = cnt[i];
      cursor[i] = run;
      dinv[i] = rsqrtf((float)v + 1.0f);
      run += v;
      row_ptr[i + 1] = run;
    }
  }
  if (tid == 0) row_ptr[0] = 0;
}

// ---------------- K4: fill adjacency ----------------
__global__ void k_fill(const int* __restrict__ ei, int* __restrict__ cursor,
                       int* __restrict__ adj, int E)
{
  int e = blockIdx.x * 256 + threadIdx.x;
  if (e < E) {
    int r = ei[e], c = ei[E + e];
    int pos = atomicAdd(&cursor[c], 1);
    adj[pos] = r;
  }
}

// ---------------- K5: fused gather + relu + Conv1d(32->64,k=2) + relu -> seq bf16 ----------------
__global__ __launch_bounds__(256) void k_gather_conv(
    const int* __restrict__ row_ptr, const int* __restrict__ adj,
    const float* __restrict__ dinv, const __hip_bfloat16* __restrict__ h,
    const float* __restrict__ gcnb,
    const float* __restrict__ Wc, const float* __restrict__ bc,
    __hip_bfloat16* __restrict__ seq, int N)
{
  __shared__ float Ws[64 * 65];   // transposed conv weights: [(ci*2+k)*65 + co]
  __shared__ float gs[8][33];
  __shared__ int   nbr[256];
  __shared__ float nbrd[256];
  int tid = threadIdx.x;
  int n = blockIdx.x;

  for (int i = tid; i < 64 * 64; i += 256) {
    int co = i >> 6, ci2 = i & 63;
    Ws[ci2 * 65 + co] = Wc[i];
  }

  int start = row_ptr[n], end = row_ptr[n + 1];
  float dn = dinv[n];
  float a0 = cvbf(h[(long)n * 256 + tid]) * dn;   // self loop
  float a1 = 0.f, a2 = 0.f, a3 = 0.f;

  for (int base = start; base < end; base += 256) {
    int m = end - base; if (m > 256) m = 256;
    __syncthreads();
    if (tid < m) {
      int src = adj[base + tid];
      nbr[tid] = src;
      nbrd[tid] = dinv[src];
    }
    __syncthreads();
    int j = 0;
    for (; j + 4 <= m; j += 4) {
      float v0 = cvbf(h[(long)nbr[j]     * 256 + tid]);
      float v1 = cvbf(h[(long)nbr[j + 1] * 256 + tid]);
      float v2 = cvbf(h[(long)nbr[j + 2] * 256 + tid]);
      float v3 = cvbf(h[(long)nbr[j + 3] * 256 + tid]);
      a0 = fmaf(v0, nbrd[j],     a0);
      a1 = fmaf(v1, nbrd[j + 1], a1);
      a2 = fmaf(v2, nbrd[j + 2], a2);
      a3 = fmaf(v3, nbrd[j + 3], a3);
    }
    for (; j < m; ++j)
      a0 = fmaf(cvbf(h[(long)nbr[j] * 256 + tid]), nbrd[j], a0);
  }
  float acc = (a0 + a1) + (a2 + a3);

  float g = fmaxf(fmaf(acc, dn, gcnb[tid & 31]), 0.f);
  gs[tid >> 5][tid & 31] = g;
  __syncthreads();

  long n64 = (long)N * 64;
  #pragma unroll
  for (int rep = 0; rep < 2; ++rep) {
    int p = rep * 256 + tid;
    if (p < 448) {
      int t = p >> 6, co = p & 63;
      float o = bc[co];
      #pragma unroll
      for (int ci = 0; ci < 32; ++ci) {
        o = fmaf(gs[t][ci],     Ws[(ci * 2)     * 65 + co], o);
        o = fmaf(gs[t + 1][ci], Ws[(ci * 2 + 1) * 65 + co], o);
      }
      seq[(long)t * n64 + (long)n * 64 + co] = __float2bfloat16(fmaxf(o, 0.f));
    }
  }
}

// ---------------- K6: pack bf16 weights ----------------
__global__ void k_prep(const float* __restrict__ Wih, const float* __restrict__ Whh,
                       const float* __restrict__ bih, const float* __restrict__ bhh,
                       const float* __restrict__ fc1W, const float* __restrict__ fc2W,
                       __hip_bfloat16* __restrict__ Wcat, float* __restrict__ bias,
                       __hip_bfloat16* __restrict__ W1b, __hip_bfloat16* __restrict__ W2b)
{
  int q = threadIdx.x;   // 512 threads
  for (int k = 0; k < 64; ++k)  Wcat[q * 192 + k]      = __float2bfloat16(Wih[q * 64 + k]);
  for (int k = 0; k < 128; ++k) Wcat[q * 192 + 64 + k] = __float2bfloat16(Whh[q * 128 + k]);
  bias[q] = bih[q] + bhh[q];
  if (q < 64)  for (int k = 0; k < 128; ++k) W1b[q * 128 + k] = __float2bfloat16(fc1W[q * 128 + k]);
  if (q < 128) for (int k = 0; k < 64;  ++k) W2b[q * 64 + k]  = __float2bfloat16(fc2W[q * 64 + k]);
}

// ---------------- K7: fused 7-step LSTM + head, 32 rows/block ----------------
// c in registers, h in LDS (bf16). Wave w owns h-cols [w*32, w*32+32) across gates.
__global__ __launch_bounds__(256) void k_lstm_head(
    const __hip_bfloat16* __restrict__ seq,   // [7][N][64]
    const __hip_bfloat16* __restrict__ Wcat,  // [512][192]
    const float* __restrict__ bias,           // [512]
    const __hip_bfloat16* __restrict__ W1b,   // [64][128]
    const float* __restrict__ fc1b,
    const __hip_bfloat16* __restrict__ W2b,   // [128][64]
    const float* __restrict__ fc2b,
    float* __restrict__ out, int N)
{
  __shared__ __hip_bfloat16 h_lds[32][136];   // 272B rows: 16B-aligned, 2-way max bank alias
  __shared__ __hip_bfloat16 s1_lds[32][72];
  int tid  = threadIdx.x;
  int wave = tid >> 6;
  int lane = tid & 63;
  int l15  = lane & 15;
  int lhi  = lane >> 4;
  long n0  = (long)blockIdx.x * 32;

  float c[2][2][4];
  #pragma unroll
  for (int mt = 0; mt < 2; ++mt)
    #pragma unroll
    for (int hf = 0; hf < 2; ++hf)
      #pragma unroll
      for (int r = 0; r < 4; ++r) c[mt][hf][r] = 0.f;

  for (int t = 0; t < 7; ++t) {
    const __hip_bfloat16* st = seq + (size_t)t * N * 64;
    f32x4 acc[2][4][2];
    #pragma unroll
    for (int mt = 0; mt < 2; ++mt)
      #pragma unroll
      for (int gg = 0; gg < 4; ++gg)
        #pragma unroll
        for (int hf = 0; hf < 2; ++hf)
          acc[mt][gg][hf] = (f32x4){0.f, 0.f, 0.f, 0.f};

    // ks 0..1: x-part from seq (global)
    #pragma unroll
    for (int ks = 0; ks < 2; ++ks) {
      int kb = ks * 32 + lhi * 8;
      bf16x8 a0 = load_bf8(st + (n0 +      l15) * 64 + kb);
      bf16x8 a1 = load_bf8(st + (n0 + 16 + l15) * 64 + kb);
      #pragma unroll
      for (int gg = 0; gg < 4; ++gg)
        #pragma unroll
        for (int hf = 0; hf < 2; ++hf) {
          int q = gg * 128 + wave * 32 + hf * 16 + l15;
          bf16x8 b = load_bf8(Wcat + q * 192 + kb);
          acc[0][gg][hf] = __builtin_amdgcn_mfma_f32_16x16x32_bf16(a0, b, acc[0][gg][hf], 0, 0, 0);
          acc[1][gg][hf] = __builtin_amdgcn_mfma_f32_16x16x32_bf16(a1, b, acc[1][gg][hf], 0, 0, 0);
        }
    }
    // ks 2..5: h-part from LDS (h==0 at t==0, skip)
    if (t > 0) {
      #pragma unroll
      for (int ks = 2; ks < 6; ++ks) {
        int koff = (ks - 2) * 32 + lhi * 8;
        int kb = ks * 32 + lhi * 8;
        bf16x8 a0 = load_bf8(&h_lds[l15][koff]);
        bf16x8 a1 = load_bf8(&h_lds[16 + l15][koff]);
        #pragma unroll
        for (int gg = 0; gg < 4; ++gg)
          #pragma unroll
          for (int hf = 0; hf < 2; ++hf) {
            int q = gg * 128 + wave * 32 + hf * 16 + l15;
            bf16x8 b = load_bf8(Wcat + q * 192 + kb);
            acc[0][gg][hf] = __builtin_amdgcn_mfma_f32_16x16x32_bf16(a0, b, acc[0][gg][hf], 0, 0, 0);
            acc[1][gg][hf] = __builtin_amdgcn_mfma_f32_16x16x32_bf16(a1, b, acc[1][gg][hf], 0, 0, 0);
          }
      }
    }
    __syncthreads();   // all h_lds reads done before overwrite

    #pragma unroll
    for (int mt = 0; mt < 2; ++mt)
      #pragma unroll
      for (int hf = 0; hf < 2; ++hf) {
        int hcol = wave * 32 + hf * 16 + l15;
        float bi = bias[hcol], bff = bias[128 + hcol], bg = bias[256 + hcol], bo = bias[384 + hcol];
        #pragma unroll
        for (int r = 0; r < 4; ++r) {
          int row = mt * 16 + lhi * 4 + r;
          float zi = acc[mt][0][hf][r] + bi;
          float zf = acc[mt][1][hf][r] + bff;
          float zg = acc[mt][2][hf][r] + bg;
          float zo = acc[mt][3][hf][r] + bo;
          float cp = c[mt][hf][r];
          float cn = sigm(zf) * cp + sigm(zi) * tanh_f(zg);
          c[mt][hf][r] = cn;
          h_lds[row][hcol] = __float2bfloat16(sigm(zo) * tanh_f(cn));
        }
      }
    __syncthreads();   // h_lds visible for next step
  }

  // ---- head stage 1: s1[32][64] = relu(h @ W1^T + b1) ----
  {
    f32x4 acc1[2];
    acc1[0] = (f32x4){0.f, 0.f, 0.f, 0.f};
    acc1[1] = (f32x4){0.f, 0.f, 0.f, 0.f};
    int col1 = wave * 16 + l15;
    #pragma unroll
    for (int ks = 0; ks < 4; ++ks) {
      int kb = ks * 32 + lhi * 8;
      bf16x8 a0 = load_bf8(&h_lds[l15][kb]);
      bf16x8 a1 = load_bf8(&h_lds[16 + l15][kb]);
      bf16x8 b = load_bf8(W1b + col1 * 128 + kb);
      acc1[0] = __builtin_amdgcn_mfma_f32_16x16x32_bf16(a0, b, acc1[0], 0, 0, 0);
      acc1[1] = __builtin_amdgcn_mfma_f32_16x16x32_bf16(a1, b, acc1[1], 0, 0, 0);
    }
    float b1 = fc1b[col1];
    #pragma unroll
    for (int mt = 0; mt < 2; ++mt)
      #pragma unroll
      for (int r = 0; r < 4; ++r) {
        int row = mt * 16 + lhi * 4 + r;
        s1_lds[row][col1] = __float2bfloat16(fmaxf(acc1[mt][r] + b1, 0.f));
      }
  }
  __syncthreads();

  // ---- head stage 2: out[32][128] = sigmoid(s1 @ W2^T + b2) ----
  {
    f32x4 acc2[2][2];
    #pragma unroll
    for (int mt = 0; mt < 2; ++mt)
      #pragma unroll
      for (int hf = 0; hf < 2; ++hf)
        acc2[mt][hf] = (f32x4){0.f, 0.f, 0.f, 0.f};
    #pragma unroll
    for (int ks = 0; ks < 2; ++ks) {
      int kb = ks * 32 + lhi * 8;
      bf16x8 a0 = load_bf8(&s1_lds[l15][kb]);
      bf16x8 a1 = load_bf8(&s1_lds[16 + l15][kb]);
      #pragma unroll
      for (int hf = 0; hf < 2; ++hf) {
        int c2 = wave * 32 + hf * 16 + l15;
        bf16x8 b = load_bf8(W2b + c2 * 64 + kb);
        acc2[0][hf] = __builtin_amdgcn_mfma_f32_16x16x32_bf16(a0, b, acc2[0][hf], 0, 0, 0);
        acc2[1][hf] = __builtin_amdgcn_mfma_f32_16x16x32_bf16(a1, b, acc2[1][hf], 0, 0, 0);
      }
    }
    #pragma unroll
    for (int hf = 0; hf < 2; ++hf) {
      int c2 = wave * 32 + hf * 16 + l15;
      float b2 = fc2b[c2];
      #pragma unroll
      for (int mt = 0; mt < 2; ++mt)
        #pragma unroll
        for (int r = 0; r < 4; ++r) {
          long row = n0 + mt * 16 + lhi * 4 + r;
          out[row * 128 + c2] = sigm(acc2[mt][hf][r] + b2);
        }
    }
  }
}

extern "C" void kernel_launch(void* const* d_in, const int* in_sizes, int n_in,
                              void* d_out, int out_size, void* d_ws, size_t ws_size,
                              hipStream_t stream)
{
  const float* x     = (const float*)d_in[0];
  const int*   ei    = (const int*)d_in[1];
  const float* gcnW  = (const float*)d_in[2];
  const float* gcnb  = (const float*)d_in[3];
  const float* convW = (const float*)d_in[4];
  const float* convb = (const float*)d_in[5];
  const float* Wih   = (const float*)d_in[6];
  const float* Whh   = (const float*)d_in[7];
  const float* bih   = (const float*)d_in[8];
  const float* bhh   = (const float*)d_in[9];
  const float* fc1W  = (const float*)d_in[10];
  const float* fc1b  = (const float*)d_in[11];
  const float* fc2W  = (const float*)d_in[12];
  const float* fc2b  = (const float*)d_in[13];

  const int N = in_sizes[0] / (T_STEPS * F_IN);
  const int E = in_sizes[1] / 2;

  char* ws = (char*)d_ws;
  size_t off = 0;
  auto alloc = [&](size_t bytes) {
    void* p = ws + off;
    off = (off + bytes + 255) & ~(size_t)255;
    return p;
  };
  __hip_bfloat16* h   = (__hip_bfloat16*)alloc((size_t)N * 256 * 2);       // [N][T*32] bf16
  __hip_bfloat16* seq = (__hip_bfloat16*)alloc((size_t)7 * N * 64 * 2);    // [7][N][64]
  int* cnt     = (int*)alloc((size_t)N * 4);
  int* row_ptr = (int*)alloc((size_t)(N + 1) * 4);
  int* cursor  = (int*)alloc((size_t)N * 4);
  float* dinv  = (float*)alloc((size_t)N * 4);
  int* adj     = (int*)alloc((size_t)E * 4);
  __hip_bfloat16* Wcat = (__hip_bfloat16*)alloc(512 * 192 * 2);
  float* bias = (float*)alloc(512 * 4);
  __hip_bfloat16* W1b = (__hip_bfloat16*)alloc(64 * 128 * 2);
  __hip_bfloat16* W2b = (__hip_bfloat16*)alloc(128 * 64 * 2);

  hipMemsetAsync(cnt, 0, (size_t)N * 4, stream);

  k_prep<<<1, 512, 0, stream>>>(Wih, Whh, bih, bhh, fc1W, fc2W, Wcat, bias, W1b, W2b);
  k_transform<<<(N * T_STEPS) / 8, 256, 0, stream>>>(x, gcnW, h);
  k_count<<<(E + 255) / 256, 256, 0, stream>>>(ei + E, cnt, E);
  k_scan<<<1, 1024, 0, stream>>>(cnt, row_ptr, cursor, dinv, N);
  k_fill<<<(E + 255) / 256, 256, 0, stream>>>(ei, cursor, adj, E);
  k_gather_conv<<<N, 256, 0, stream>>>(row_ptr, adj, dinv, h, gcnb, convW, convb, seq, N);
  k_lstm_head<<<N / 32, 256, 0, stream>>>(seq, Wcat, bias, W1b, fc1b, W2b, fc2b, (float*)d_out, N);
}

// Round 4
// 419.004 us; speedup vs baseline: 1.8886x; 1.0090x over previous
//
#include <hip/hip_runtime.h>
#include <hip/hip_bf16.h>

#define T_STEPS 8
#define F_IN    128
#define H_GCN   32
#define H_CONV  64
#define H_LSTM  128

typedef __bf16 bf16x8 __attribute__((ext_vector_type(8)));
typedef float  f32x4  __attribute__((ext_vector_type(4)));

__device__ __forceinline__ float sigm(float x)   { return 1.f / (1.f + __expf(-x)); }
__device__ __forceinline__ float tanh_f(float x) { return 1.f - 2.f / (__expf(2.f * x) + 1.f); }
__device__ __forceinline__ float cvbf(__hip_bfloat16 v) { return __bfloat162float(v); }

__device__ __forceinline__ bf16x8 load_bf8(const __hip_bfloat16* p) {
  int4 v = *reinterpret_cast<const int4*>(p);
  return __builtin_bit_cast(bf16x8, v);
}

// ---------------- K1: h[r][o] = x[r][:] @ gcn_W[:,o], bf16 out ----------------
__global__ __launch_bounds__(256) void k_transform(const float* __restrict__ x,
                                                   const float* __restrict__ W,
                                                   __hip_bfloat16* __restrict__ h)
{
  __shared__ float Ws[F_IN * H_GCN];
  __shared__ float xs[8][F_IN];
  int tid = threadIdx.x;
  for (int i = tid; i < F_IN * H_GCN; i += 256) Ws[i] = W[i];
  long r0 = (long)blockIdx.x * 8;
  int idx = tid * 4;
  float4 xv = *reinterpret_cast<const float4*>(x + r0 * F_IN + idx);
  int rl = idx >> 7, c0 = idx & 127;
  xs[rl][c0] = xv.x; xs[rl][c0 + 1] = xv.y; xs[rl][c0 + 2] = xv.z; xs[rl][c0 + 3] = xv.w;
  __syncthreads();
  int rr = tid >> 5, o = tid & 31;
  float acc = 0.f;
  #pragma unroll 8
  for (int f = 0; f < F_IN; f += 4) {
    float4 x4 = *reinterpret_cast<const float4*>(&xs[rr][f]);
    acc = fmaf(x4.x, Ws[(f + 0) * H_GCN + o], acc);
    acc = fmaf(x4.y, Ws[(f + 1) * H_GCN + o], acc);
    acc = fmaf(x4.z, Ws[(f + 2) * H_GCN + o], acc);
    acc = fmaf(x4.w, Ws[(f + 3) * H_GCN + o], acc);
  }
  h[(r0 + rr) * H_GCN + o] = __float2bfloat16(acc);
}

// ---------------- K2: in-degree count ----------------
__global__ void k_count(const int* __restrict__ col, int* __restrict__ cnt, int E)
{
  int i = blockIdx.x * 256 + threadIdx.x;
  if (i < E) atomicAdd(&cnt[col[i]], 1);
}

// ---------------- K3: single-block chunked scan -> row_ptr, cursor, dinv ----------------
__global__ __launch_bounds__(1024) void k_scan(const int* __restrict__ cnt,
                                               int* __restrict__ row_ptr,
                                               int* __restrict__ cursor,
                                               float* __restrict__ dinv, int N)
{
  __shared__ int s[1024];
  int tid = threadIdx.x;
  const int CH = (N + 1023) >> 10;
  int i0 = tid * CH;
  int sum = 0;
  for (int j = 0; j < CH; ++j) {
    int i = i0 + j;
    sum += (i < N) ? cnt[i] : 0;
  }
  s[tid] = sum;
  __syncthreads();
  #pragma unroll
  for (int off = 1; off < 1024; off <<= 1) {
    int t = (tid >= off) ? s[tid - off] : 0;
    __syncthreads();
    s[tid] += t;
    __syncthreads();
  }
  int run = (tid > 0) ? s[tid - 1] : 0;
  for (int j = 0; j < CH; ++j) {
    int i = i0 + j;
    if (i < N) {
      int v = cnt[i];
      cursor[i] = run;
      dinv[i] = rsqrtf((float)v + 1.0f);
      run += v;
      row_ptr[i + 1] = run;
    }
  }
  if (tid == 0) row_ptr[0] = 0;
}

// ---------------- K4: fill adjacency ----------------
__global__ void k_fill(const int* __restrict__ ei, int* __restrict__ cursor,
                       int* __restrict__ adj, int E)
{
  int e = blockIdx.x * 256 + threadIdx.x;
  if (e < E) {
    int r = ei[e], c = ei[E + e];
    int pos = atomicAdd(&cursor[c], 1);
    adj[pos] = r;
  }
}

// ---------------- K5: fused gather + relu + Conv1d + relu, 2 nodes/block ----------------
__global__ __launch_bounds__(256) void k_gather_conv(
    const int* __restrict__ row_ptr, const int* __restrict__ adj,
    const float* __restrict__ dinv, const __hip_bfloat16* __restrict__ h,
    const float* __restrict__ gcnb,
    const float* __restrict__ Wc, const float* __restrict__ bc,
    __hip_bfloat16* __restrict__ seq, int N)
{
  __shared__ float Ws[64 * 65];   // transposed conv weights: [(ci*2+k)*65 + co]
  __shared__ float gs[8][33];
  __shared__ int   nbr[256];
  __shared__ float nbrd[256];
  int tid = threadIdx.x;

  for (int i = tid; i < 64 * 64; i += 256) {
    int co = i >> 6, ci2 = i & 63;
    Ws[ci2 * 65 + co] = Wc[i];
  }

  long n64 = (long)N * 64;
  for (int nl = 0; nl < 2; ++nl) {
    int n = blockIdx.x * 2 + nl;

    int start = row_ptr[n], end = row_ptr[n + 1];
    float dn = dinv[n];
    float a0 = cvbf(h[(long)n * 256 + tid]) * dn;   // self loop
    float a1 = 0.f, a2 = 0.f, a3 = 0.f;

    for (int base = start; base < end; base += 256) {
      int m = end - base; if (m > 256) m = 256;
      __syncthreads();
      if (tid < m) {
        int src = adj[base + tid];
        nbr[tid] = src;
        nbrd[tid] = dinv[src];
      }
      __syncthreads();
      int j = 0;
      for (; j + 4 <= m; j += 4) {
        float v0 = cvbf(h[(long)nbr[j]     * 256 + tid]);
        float v1 = cvbf(h[(long)nbr[j + 1] * 256 + tid]);
        float v2 = cvbf(h[(long)nbr[j + 2] * 256 + tid]);
        float v3 = cvbf(h[(long)nbr[j + 3] * 256 + tid]);
        a0 = fmaf(v0, nbrd[j],     a0);
        a1 = fmaf(v1, nbrd[j + 1], a1);
        a2 = fmaf(v2, nbrd[j + 2], a2);
        a3 = fmaf(v3, nbrd[j + 3], a3);
      }
      for (; j < m; ++j)
        a0 = fmaf(cvbf(h[(long)nbr[j] * 256 + tid]), nbrd[j], a0);
    }
    float acc = (a0 + a1) + (a2 + a3);

    float g = fmaxf(fmaf(acc, dn, gcnb[tid & 31]), 0.f);
    gs[tid >> 5][tid & 31] = g;
    __syncthreads();

    #pragma unroll
    for (int rep = 0; rep < 2; ++rep) {
      int p = rep * 256 + tid;
      if (p < 448) {
        int t = p >> 6, co = p & 63;
        float o = bc[co];
        #pragma unroll
        for (int ci = 0; ci < 32; ++ci) {
          o = fmaf(gs[t][ci],     Ws[(ci * 2)     * 65 + co], o);
          o = fmaf(gs[t + 1][ci], Ws[(ci * 2 + 1) * 65 + co], o);
        }
        seq[(long)t * n64 + (long)n * 64 + co] = __float2bfloat16(fmaxf(o, 0.f));
      }
    }
    __syncthreads();   // gs/nbr reuse hazard for next node
  }
}

// ---------------- K6: pack bf16 weights ----------------
__global__ void k_prep(const float* __restrict__ Wih, const float* __restrict__ Whh,
                       const float* __restrict__ bih, const float* __restrict__ bhh,
                       const float* __restrict__ fc1W, const float* __restrict__ fc2W,
                       __hip_bfloat16* __restrict__ Wcat, float* __restrict__ bias,
                       __hip_bfloat16* __restrict__ W1b, __hip_bfloat16* __restrict__ W2b)
{
  int q = threadIdx.x;   // 512 threads
  for (int k = 0; k < 64; ++k)  Wcat[q * 192 + k]      = __float2bfloat16(Wih[q * 64 + k]);
  for (int k = 0; k < 128; ++k) Wcat[q * 192 + 64 + k] = __float2bfloat16(Whh[q * 128 + k]);
  bias[q] = bih[q] + bhh[q];
  if (q < 64)  for (int k = 0; k < 128; ++k) W1b[q * 128 + k] = __float2bfloat16(fc1W[q * 128 + k]);
  if (q < 128) for (int k = 0; k < 64;  ++k) W2b[q * 64 + k]  = __float2bfloat16(fc2W[q * 64 + k]);
}

// ---------------- K7: fused 7-step LSTM + head ----------------
// 512 threads = 8 waves; 16 rows/block (grid N/16); wave w owns h-cols
// [w*16, w*16+16) across all 4 gates. c in regs (4/thread), h in LDS bf16.
__global__ __launch_bounds__(512) void k_lstm_head(
    const __hip_bfloat16* __restrict__ seq,   // [7][N][64]
    const __hip_bfloat16* __restrict__ Wcat,  // [512][192]
    const float* __restrict__ bias,           // [512]
    const __hip_bfloat16* __restrict__ W1b,   // [64][128]
    const float* __restrict__ fc1b,
    const __hip_bfloat16* __restrict__ W2b,   // [128][64]
    const float* __restrict__ fc2b,
    float* __restrict__ out, int N)
{
  __shared__ __hip_bfloat16 h_lds[16][136];   // 272B rows -> worst 2-way bank alias (free)
  __shared__ __hip_bfloat16 s1_lds[16][72];
  int tid  = threadIdx.x;
  int wave = tid >> 6;
  int lane = tid & 63;
  int l15  = lane & 15;
  int lhi  = lane >> 4;
  long n0  = (long)blockIdx.x * 16;
  int hc   = wave * 16 + l15;                 // this thread's h-column

  float c[4] = {0.f, 0.f, 0.f, 0.f};

  for (int t = 0; t < 7; ++t) {
    const __hip_bfloat16* st = seq + (size_t)t * N * 64;
    f32x4 acc[4];
    #pragma unroll
    for (int gg = 0; gg < 4; ++gg) acc[gg] = (f32x4){0.f, 0.f, 0.f, 0.f};

    // x-part: K = 64 from seq (global)
    #pragma unroll
    for (int ks = 0; ks < 2; ++ks) {
      int kb = ks * 32 + lhi * 8;
      bf16x8 a = load_bf8(st + (n0 + l15) * 64 + kb);
      #pragma unroll
      for (int gg = 0; gg < 4; ++gg) {
        bf16x8 b = load_bf8(Wcat + (gg * 128 + hc) * 192 + kb);
        acc[gg] = __builtin_amdgcn_mfma_f32_16x16x32_bf16(a, b, acc[gg], 0, 0, 0);
      }
    }
    // h-part: K = 128 from LDS (skip at t==0, h==0)
    if (t > 0) {
      #pragma unroll
      for (int ks = 2; ks < 6; ++ks) {
        int kb = ks * 32 + lhi * 8;
        bf16x8 a = load_bf8(&h_lds[l15][kb - 64]);
        #pragma unroll
        for (int gg = 0; gg < 4; ++gg) {
          bf16x8 b = load_bf8(Wcat + (gg * 128 + hc) * 192 + kb);
          acc[gg] = __builtin_amdgcn_mfma_f32_16x16x32_bf16(a, b, acc[gg], 0, 0, 0);
        }
      }
    }
    __syncthreads();   // h_lds reads done before overwrite

    float bi = bias[hc], bff = bias[128 + hc], bg = bias[256 + hc], bo = bias[384 + hc];
    #pragma unroll
    for (int r = 0; r < 4; ++r) {
      float zi = acc[0][r] + bi;
      float zf = acc[1][r] + bff;
      float zg = acc[2][r] + bg;
      float zo = acc[3][r] + bo;
      float cn = sigm(zf) * c[r] + sigm(zi) * tanh_f(zg);
      c[r] = cn;
      h_lds[lhi * 4 + r][hc] = __float2bfloat16(sigm(zo) * tanh_f(cn));
    }
    __syncthreads();   // h_lds visible for next step
  }

  // ---- head stage 1: s1[16][64] = relu(h @ W1^T + b1), waves 0-3 ----
  if (wave < 4) {
    int col1 = wave * 16 + l15;
    f32x4 acc1 = (f32x4){0.f, 0.f, 0.f, 0.f};
    #pragma unroll
    for (int ks = 0; ks < 4; ++ks) {
      int kb = ks * 32 + lhi * 8;
      bf16x8 a = load_bf8(&h_lds[l15][kb]);
      bf16x8 b = load_bf8(W1b + col1 * 128 + kb);
      acc1 = __builtin_amdgcn_mfma_f32_16x16x32_bf16(a, b, acc1, 0, 0, 0);
    }
    float b1 = fc1b[col1];
    #pragma unroll
    for (int r = 0; r < 4; ++r)
      s1_lds[lhi * 4 + r][col1] = __float2bfloat16(fmaxf(acc1[r] + b1, 0.f));
  }
  __syncthreads();

  // ---- head stage 2: out[16][128] = sigmoid(s1 @ W2^T + b2), all 8 waves ----
  {
    int c2 = wave * 16 + l15;
    f32x4 acc2 = (f32x4){0.f, 0.f, 0.f, 0.f};
    #pragma unroll
    for (int ks = 0; ks < 2; ++ks) {
      int kb = ks * 32 + lhi * 8;
      bf16x8 a = load_bf8(&s1_lds[l15][kb]);
      bf16x8 b = load_bf8(W2b + c2 * 64 + kb);
      acc2 = __builtin_amdgcn_mfma_f32_16x16x32_bf16(a, b, acc2, 0, 0, 0);
    }
    float b2 = fc2b[c2];
    #pragma unroll
    for (int r = 0; r < 4; ++r)
      out[(n0 + lhi * 4 + r) * 128 + c2] = sigm(acc2[r] + b2);
  }
}

extern "C" void kernel_launch(void* const* d_in, const int* in_sizes, int n_in,
                              void* d_out, int out_size, void* d_ws, size_t ws_size,
                              hipStream_t stream)
{
  const float* x     = (const float*)d_in[0];
  const int*   ei    = (const int*)d_in[1];
  const float* gcnW  = (const float*)d_in[2];
  const float* gcnb  = (const float*)d_in[3];
  const float* convW = (const float*)d_in[4];
  const float* convb = (const float*)d_in[5];
  const float* Wih   = (const float*)d_in[6];
  const float* Whh   = (const float*)d_in[7];
  const float* bih   = (const float*)d_in[8];
  const float* bhh   = (const float*)d_in[9];
  const float* fc1W  = (const float*)d_in[10];
  const float* fc1b  = (const float*)d_in[11];
  const float* fc2W  = (const float*)d_in[12];
  const float* fc2b  = (const float*)d_in[13];

  const int N = in_sizes[0] / (T_STEPS * F_IN);
  const int E = in_sizes[1] / 2;

  char* ws = (char*)d_ws;
  size_t off = 0;
  auto alloc = [&](size_t bytes) {
    void* p = ws + off;
    off = (off + bytes + 255) & ~(size_t)255;
    return p;
  };
  __hip_bfloat16* h   = (__hip_bfloat16*)alloc((size_t)N * 256 * 2);       // [N][T*32] bf16
  __hip_bfloat16* seq = (__hip_bfloat16*)alloc((size_t)7 * N * 64 * 2);    // [7][N][64]
  int* cnt     = (int*)alloc((size_t)N * 4);
  int* row_ptr = (int*)alloc((size_t)(N + 1) * 4);
  int* cursor  = (int*)alloc((size_t)N * 4);
  float* dinv  = (float*)alloc((size_t)N * 4);
  int* adj     = (int*)alloc((size_t)E * 4);
  __hip_bfloat16* Wcat = (__hip_bfloat16*)alloc(512 * 192 * 2);
  float* bias = (float*)alloc(512 * 4);
  __hip_bfloat16* W1b = (__hip_bfloat16*)alloc(64 * 128 * 2);
  __hip_bfloat16* W2b = (__hip_bfloat16*)alloc(128 * 64 * 2);

  hipMemsetAsync(cnt, 0, (size_t)N * 4, stream);

  k_prep<<<1, 512, 0, stream>>>(Wih, Whh, bih, bhh, fc1W, fc2W, Wcat, bias, W1b, W2b);
  k_transform<<<(N * T_STEPS) / 8, 256, 0, stream>>>(x, gcnW, h);
  k_count<<<(E + 255) / 256, 256, 0, stream>>>(ei + E, cnt, E);
  k_scan<<<1, 1024, 0, stream>>>(cnt, row_ptr, cursor, dinv, N);
  k_fill<<<(E + 255) / 256, 256, 0, stream>>>(ei, cursor, adj, E);
  k_gather_conv<<<N / 2, 256, 0, stream>>>(row_ptr, adj, dinv, h, gcnb, convW, convb, seq, N);
  k_lstm_head<<<N / 16, 512, 0, stream>>>(seq, Wcat, bias, W1b, fc1b, W2b, fc2b, (float*)d_out, N);
}

// Round 5
// 385.913 us; speedup vs baseline: 2.0506x; 1.0857x over previous
//
#include <hip/hip_runtime.h>
#include <hip/hip_bf16.h>

#define T_STEPS 8
#define F_IN    128
#define H_GCN   32
#define H_CONV  64
#define H_LSTM  128

typedef __bf16 bf16x8 __attribute__((ext_vector_type(8)));
typedef float  f32x4  __attribute__((ext_vector_type(4)));

__device__ __forceinline__ float sigm(float x)   { return 1.f / (1.f + __expf(-x)); }
__device__ __forceinline__ float tanh_f(float x) { return 1.f - 2.f / (__expf(2.f * x) + 1.f); }

__device__ __forceinline__ float ubf(unsigned short u) {
  union { unsigned int i; float f; } v; v.i = ((unsigned int)u) << 16; return v.f;
}

__device__ __forceinline__ bf16x8 load_bf8(const __hip_bfloat16* p) {
  int4 v = *reinterpret_cast<const int4*>(p);
  return __builtin_bit_cast(bf16x8, v);
}

// ---------------- K1: h[r][o] = x[r][:] @ gcn_W[:,o], bf16 out ----------------
__global__ __launch_bounds__(256) void k_transform(const float* __restrict__ x,
                                                   const float* __restrict__ W,
                                                   __hip_bfloat16* __restrict__ h)
{
  __shared__ float Ws[F_IN * H_GCN];
  __shared__ float xs[8][F_IN];
  int tid = threadIdx.x;
  for (int i = tid; i < F_IN * H_GCN; i += 256) Ws[i] = W[i];
  long r0 = (long)blockIdx.x * 8;
  int idx = tid * 4;
  float4 xv = *reinterpret_cast<const float4*>(x + r0 * F_IN + idx);
  int rl = idx >> 7, c0 = idx & 127;
  xs[rl][c0] = xv.x; xs[rl][c0 + 1] = xv.y; xs[rl][c0 + 2] = xv.z; xs[rl][c0 + 3] = xv.w;
  __syncthreads();
  int rr = tid >> 5, o = tid & 31;
  float acc = 0.f;
  #pragma unroll 8
  for (int f = 0; f < F_IN; f += 4) {
    float4 x4 = *reinterpret_cast<const float4*>(&xs[rr][f]);
    acc = fmaf(x4.x, Ws[(f + 0) * H_GCN + o], acc);
    acc = fmaf(x4.y, Ws[(f + 1) * H_GCN + o], acc);
    acc = fmaf(x4.z, Ws[(f + 2) * H_GCN + o], acc);
    acc = fmaf(x4.w, Ws[(f + 3) * H_GCN + o], acc);
  }
  h[(r0 + rr) * H_GCN + o] = __float2bfloat16(acc);
}

// ---------------- K2: in-degree count ----------------
__global__ void k_count(const int* __restrict__ col, int* __restrict__ cnt, int E)
{
  int i = blockIdx.x * 256 + threadIdx.x;
  if (i < E) atomicAdd(&cnt[col[i]], 1);
}

// ---------------- K3: single-block chunked scan -> row_ptr, cursor, dinv ----------------
__global__ __launch_bounds__(1024) void k_scan(const int* __restrict__ cnt,
                                               int* __restrict__ row_ptr,
                                               int* __restrict__ cursor,
                                               float* __restrict__ dinv, int N)
{
  __shared__ int s[1024];
  int tid = threadIdx.x;
  const int CH = (N + 1023) >> 10;
  int i0 = tid * CH;
  int sum = 0;
  for (int j = 0; j < CH; ++j) {
    int i = i0 + j;
    sum += (i < N) ? cnt[i] : 0;
  }
  s[tid] = sum;
  __syncthreads();
  #pragma unroll
  for (int off = 1; off < 1024; off <<= 1) {
    int t = (tid >= off) ? s[tid - off] : 0;
    __syncthreads();
    s[tid] += t;
    __syncthreads();
  }
  int run = (tid > 0) ? s[tid - 1] : 0;
  for (int j = 0; j < CH; ++j) {
    int i = i0 + j;
    if (i < N) {
      int v = cnt[i];
      cursor[i] = run;
      dinv[i] = rsqrtf((float)v + 1.0f);
      run += v;
      row_ptr[i + 1] = run;
    }
  }
  if (tid == 0) row_ptr[0] = 0;
}

// ---------------- K4: fill adjacency ----------------
__global__ void k_fill(const int* __restrict__ ei, int* __restrict__ cursor,
                       int* __restrict__ adj, int E)
{
  int e = blockIdx.x * 256 + threadIdx.x;
  if (e < E) {
    int r = ei[e], c = ei[E + e];
    int pos = atomicAdd(&cursor[c], 1);
    adj[pos] = r;
  }
}

// ---------------- K5: fused gather + relu + Conv1d + relu ----------------
// 4 nodes per block, ONE WAVE PER NODE (concurrent, no barriers in gather).
// Lane owns 4 h-columns (8B loads). Neighbor loop pipelined 16-deep.
__global__ __launch_bounds__(256) void k_gather_conv(
    const int* __restrict__ row_ptr, const int* __restrict__ adj,
    const float* __restrict__ dinv, const __hip_bfloat16* __restrict__ h,
    const float* __restrict__ gcnb,
    const float* __restrict__ Wc, const float* __restrict__ bc,
    __hip_bfloat16* __restrict__ seq, int N)
{
  __shared__ float Ws[64 * 65];   // transposed conv weights: [(ci*2+k)*65 + co]
  __shared__ float gs[4][8][33];  // [node][t][ci]
  int tid  = threadIdx.x;
  int wave = tid >> 6;
  int lane = tid & 63;

  for (int i = tid; i < 64 * 64; i += 256) {
    int co = i >> 6, ci2 = i & 63;
    Ws[ci2 * 65 + co] = Wc[i];
  }

  int n = blockIdx.x * 4 + wave;
  int start = row_ptr[n], end = row_ptr[n + 1];
  float dn = dinv[n];

  float acc0, acc1, acc2, acc3;
  {
    ushort4 hv = *reinterpret_cast<const ushort4*>(h + (size_t)n * 256 + lane * 4);
    acc0 = ubf(hv.x) * dn; acc1 = ubf(hv.y) * dn;
    acc2 = ubf(hv.z) * dn; acc3 = ubf(hv.w) * dn;
  }

  for (int base = start; base < end; base += 16) {
    int m = end - base; if (m > 16) m = 16;
    int srcs[16]; float ds[16]; ushort4 rv[16];
    #pragma unroll
    for (int k = 0; k < 16; ++k) if (k < m) srcs[k] = adj[base + k];
    #pragma unroll
    for (int k = 0; k < 16; ++k) if (k < m) ds[k] = dinv[srcs[k]];
    #pragma unroll
    for (int k = 0; k < 16; ++k) if (k < m)
      rv[k] = *reinterpret_cast<const ushort4*>(h + (size_t)srcs[k] * 256 + lane * 4);
    #pragma unroll
    for (int k = 0; k < 16; ++k) if (k < m) {
      acc0 = fmaf(ubf(rv[k].x), ds[k], acc0);
      acc1 = fmaf(ubf(rv[k].y), ds[k], acc1);
      acc2 = fmaf(ubf(rv[k].z), ds[k], acc2);
      acc3 = fmaf(ubf(rv[k].w), ds[k], acc3);
    }
  }

  int col0 = lane * 4;             // 4-aligned: all 4 cols share t
  int t0 = col0 >> 5, ci0 = col0 & 31;
  gs[wave][t0][ci0 + 0] = fmaxf(fmaf(acc0, dn, gcnb[ci0 + 0]), 0.f);
  gs[wave][t0][ci0 + 1] = fmaxf(fmaf(acc1, dn, gcnb[ci0 + 1]), 0.f);
  gs[wave][t0][ci0 + 2] = fmaxf(fmaf(acc2, dn, gcnb[ci0 + 2]), 0.f);
  gs[wave][t0][ci0 + 3] = fmaxf(fmaf(acc3, dn, gcnb[ci0 + 3]), 0.f);
  __syncthreads();

  // conv: 4 nodes x 7 t x 64 co = 1792 outputs = 7 per thread
  long n64 = (long)N * 64;
  #pragma unroll
  for (int rep = 0; rep < 7; ++rep) {
    int p = rep * 256 + tid;
    int nl = p / 448;
    int q  = p - nl * 448;
    int t = q >> 6, co = q & 63;
    float o = bc[co];
    #pragma unroll
    for (int ci = 0; ci < 32; ++ci) {
      o = fmaf(gs[nl][t][ci],     Ws[(ci * 2)     * 65 + co], o);
      o = fmaf(gs[nl][t + 1][ci], Ws[(ci * 2 + 1) * 65 + co], o);
    }
    int nn = blockIdx.x * 4 + nl;
    seq[(long)t * n64 + (long)nn * 64 + co] = __float2bfloat16(fmaxf(o, 0.f));
  }
}

// ---------------- K6: pack bf16 weights ----------------
__global__ void k_prep(const float* __restrict__ Wih, const float* __restrict__ Whh,
                       const float* __restrict__ bih, const float* __restrict__ bhh,
                       const float* __restrict__ fc1W, const float* __restrict__ fc2W,
                       __hip_bfloat16* __restrict__ Wcat, float* __restrict__ bias,
                       __hip_bfloat16* __restrict__ W1b, __hip_bfloat16* __restrict__ W2b)
{
  int q = threadIdx.x;   // 512 threads
  for (int k = 0; k < 64; ++k)  Wcat[q * 192 + k]      = __float2bfloat16(Wih[q * 64 + k]);
  for (int k = 0; k < 128; ++k) Wcat[q * 192 + 64 + k] = __float2bfloat16(Whh[q * 128 + k]);
  bias[q] = bih[q] + bhh[q];
  if (q < 64)  for (int k = 0; k < 128; ++k) W1b[q * 128 + k] = __float2bfloat16(fc1W[q * 128 + k]);
  if (q < 128) for (int k = 0; k < 64;  ++k) W2b[q * 64 + k]  = __float2bfloat16(fc2W[q * 64 + k]);
}

// ---------------- K7: fused 7-step LSTM + head ----------------
// 512 threads = 8 waves; 16 rows/block; wave owns 16 gate-cols across all 4 gates.
// ALL B-fragments (24 x bf16x8 = 96 VGPR) hoisted into registers before the
// t-loop -> zero in-loop global B traffic. seq A-loads prefetched one t ahead.
__global__ __launch_bounds__(512) void k_lstm_head(
    const __hip_bfloat16* __restrict__ seq,   // [7][N][64]
    const __hip_bfloat16* __restrict__ Wcat,  // [512][192]
    const float* __restrict__ bias,           // [512]
    const __hip_bfloat16* __restrict__ W1b,   // [64][128]
    const float* __restrict__ fc1b,
    const __hip_bfloat16* __restrict__ W2b,   // [128][64]
    const float* __restrict__ fc2b,
    float* __restrict__ out, int N)
{
  __shared__ __hip_bfloat16 h_lds[16][136];
  __shared__ __hip_bfloat16 s1_lds[16][72];
  int tid  = threadIdx.x;
  int wave = tid >> 6;
  int lane = tid & 63;
  int l15  = lane & 15;
  int lhi  = lane >> 4;
  long n0  = (long)blockIdx.x * 16;
  int hc   = wave * 16 + l15;

  // hoist all B fragments for this wave's 64 Wcat rows into registers
  bf16x8 bw[6][4];
  #pragma unroll
  for (int ks = 0; ks < 6; ++ks)
    #pragma unroll
    for (int gg = 0; gg < 4; ++gg)
      bw[ks][gg] = load_bf8(Wcat + (size_t)(gg * 128 + hc) * 192 + ks * 32 + lhi * 8);

  float bi = bias[hc], bff = bias[128 + hc], bg = bias[256 + hc], bo = bias[384 + hc];
  float c[4] = {0.f, 0.f, 0.f, 0.f};

  const __hip_bfloat16* sp = seq + (n0 + l15) * 64 + lhi * 8;
  size_t tstr = (size_t)N * 64;
  bf16x8 ax0 = load_bf8(sp);
  bf16x8 ax1 = load_bf8(sp + 32);

  for (int t = 0; t < 7; ++t) {
    bf16x8 nx0, nx1;
    if (t < 6) {                      // prefetch next step's A (hides L2/L3 latency)
      nx0 = load_bf8(sp + (size_t)(t + 1) * tstr);
      nx1 = load_bf8(sp + (size_t)(t + 1) * tstr + 32);
    }
    f32x4 acc[4];
    #pragma unroll
    for (int gg = 0; gg < 4; ++gg) acc[gg] = (f32x4){0.f, 0.f, 0.f, 0.f};

    #pragma unroll
    for (int gg = 0; gg < 4; ++gg)
      acc[gg] = __builtin_amdgcn_mfma_f32_16x16x32_bf16(ax0, bw[0][gg], acc[gg], 0, 0, 0);
    #pragma unroll
    for (int gg = 0; gg < 4; ++gg)
      acc[gg] = __builtin_amdgcn_mfma_f32_16x16x32_bf16(ax1, bw[1][gg], acc[gg], 0, 0, 0);

    if (t > 0) {
      #pragma unroll
      for (int ks = 2; ks < 6; ++ks) {
        bf16x8 a = load_bf8(&h_lds[l15][(ks - 2) * 32 + lhi * 8]);
        #pragma unroll
        for (int gg = 0; gg < 4; ++gg)
          acc[gg] = __builtin_amdgcn_mfma_f32_16x16x32_bf16(a, bw[ks][gg], acc[gg], 0, 0, 0);
      }
    }
    __syncthreads();   // h_lds reads done before overwrite

    #pragma unroll
    for (int r = 0; r < 4; ++r) {
      float zi = acc[0][r] + bi;
      float zf = acc[1][r] + bff;
      float zg = acc[2][r] + bg;
      float zo = acc[3][r] + bo;
      float cn = sigm(zf) * c[r] + sigm(zi) * tanh_f(zg);
      c[r] = cn;
      h_lds[lhi * 4 + r][hc] = __float2bfloat16(sigm(zo) * tanh_f(cn));
    }
    __syncthreads();   // h_lds visible for next step

    ax0 = nx0; ax1 = nx1;
  }

  // ---- head stage 1: s1[16][64] = relu(h @ W1^T + b1), waves 0-3 ----
  if (wave < 4) {
    int col1 = wave * 16 + l15;
    f32x4 acc1 = (f32x4){0.f, 0.f, 0.f, 0.f};
    #pragma unroll
    for (int ks = 0; ks < 4; ++ks) {
      int kb = ks * 32 + lhi * 8;
      bf16x8 a = load_bf8(&h_lds[l15][kb]);
      bf16x8 b = load_bf8(W1b + col1 * 128 + kb);
      acc1 = __builtin_amdgcn_mfma_f32_16x16x32_bf16(a, b, acc1, 0, 0, 0);
    }
    float b1 = fc1b[col1];
    #pragma unroll
    for (int r = 0; r < 4; ++r)
      s1_lds[lhi * 4 + r][col1] = __float2bfloat16(fmaxf(acc1[r] + b1, 0.f));
  }
  __syncthreads();

  // ---- head stage 2: out[16][128] = sigmoid(s1 @ W2^T + b2), all 8 waves ----
  {
    int c2 = wave * 16 + l15;
    f32x4 acc2 = (f32x4){0.f, 0.f, 0.f, 0.f};
    #pragma unroll
    for (int ks = 0; ks < 2; ++ks) {
      int kb = ks * 32 + lhi * 8;
      bf16x8 a = load_bf8(&s1_lds[l15][kb]);
      bf16x8 b = load_bf8(W2b + c2 * 64 + kb);
      acc2 = __builtin_amdgcn_mfma_f32_16x16x32_bf16(a, b, acc2, 0, 0, 0);
    }
    float b2 = fc2b[c2];
    #pragma unroll
    for (int r = 0; r < 4; ++r)
      out[(n0 + lhi * 4 + r) * 128 + c2] = sigm(acc2[r] + b2);
  }
}

extern "C" void kernel_launch(void* const* d_in, const int* in_sizes, int n_in,
                              void* d_out, int out_size, void* d_ws, size_t ws_size,
                              hipStream_t stream)
{
  const float* x     = (const float*)d_in[0];
  const int*   ei    = (const int*)d_in[1];
  const float* gcnW  = (const float*)d_in[2];
  const float* gcnb  = (const float*)d_in[3];
  const float* convW = (const float*)d_in[4];
  const float* convb = (const float*)d_in[5];
  const float* Wih   = (const float*)d_in[6];
  const float* Whh   = (const float*)d_in[7];
  const float* bih   = (const float*)d_in[8];
  const float* bhh   = (const float*)d_in[9];
  const float* fc1W  = (const float*)d_in[10];
  const float* fc1b  = (const float*)d_in[11];
  const float* fc2W  = (const float*)d_in[12];
  const float* fc2b  = (const float*)d_in[13];

  const int N = in_sizes[0] / (T_STEPS * F_IN);
  const int E = in_sizes[1] / 2;

  char* ws = (char*)d_ws;
  size_t off = 0;
  auto alloc = [&](size_t bytes) {
    void* p = ws + off;
    off = (off + bytes + 255) & ~(size_t)255;
    return p;
  };
  __hip_bfloat16* h   = (__hip_bfloat16*)alloc((size_t)N * 256 * 2);       // [N][T*32] bf16
  __hip_bfloat16* seq = (__hip_bfloat16*)alloc((size_t)7 * N * 64 * 2);    // [7][N][64]
  int* cnt     = (int*)alloc((size_t)N * 4);
  int* row_ptr = (int*)alloc((size_t)(N + 1) * 4);
  int* cursor  = (int*)alloc((size_t)N * 4);
  float* dinv  = (float*)alloc((size_t)N * 4);
  int* adj     = (int*)alloc((size_t)E * 4);
  __hip_bfloat16* Wcat = (__hip_bfloat16*)alloc(512 * 192 * 2);
  float* bias = (float*)alloc(512 * 4);
  __hip_bfloat16* W1b = (__hip_bfloat16*)alloc(64 * 128 * 2);
  __hip_bfloat16* W2b = (__hip_bfloat16*)alloc(128 * 64 * 2);

  hipMemsetAsync(cnt, 0, (size_t)N * 4, stream);

  k_prep<<<1, 512, 0, stream>>>(Wih, Whh, bih, bhh, fc1W, fc2W, Wcat, bias, W1b, W2b);
  k_transform<<<(N * T_STEPS) / 8, 256, 0, stream>>>(x, gcnW, h);
  k_count<<<(E + 255) / 256, 256, 0, stream>>>(ei + E, cnt, E);
  k_scan<<<1, 1024, 0, stream>>>(cnt, row_ptr, cursor, dinv, N);
  k_fill<<<(E + 255) / 256, 256, 0, stream>>>(ei, cursor, adj, E);
  k_gather_conv<<<N / 4, 256, 0, stream>>>(row_ptr, adj, dinv, h, gcnb, convW, convb, seq, N);
  k_lstm_head<<<N / 16, 512, 0, stream>>>(seq, Wcat, bias, W1b, fc1b, W2b, fc2b, (float*)d_out, N);
}

// Round 6
// 351.330 us; speedup vs baseline: 2.2524x; 1.0984x over previous
//
#include <hip/hip_runtime.h>
#include <hip/hip_bf16.h>

#define T_STEPS 8
#define F_IN    128
#define H_GCN   32
#define H_CONV  64
#define H_LSTM  128

typedef __bf16 bf16x8 __attribute__((ext_vector_type(8)));
typedef float  f32x4  __attribute__((ext_vector_type(4)));

__device__ __forceinline__ float sigm(float x)   { return 1.f / (1.f + __expf(-x)); }
__device__ __forceinline__ float tanh_f(float x) { return 1.f - 2.f / (__expf(2.f * x) + 1.f); }

__device__ __forceinline__ float ubf(unsigned short u) {
  union { unsigned int i; float f; } v; v.i = ((unsigned int)u) << 16; return v.f;
}

__device__ __forceinline__ bf16x8 load_bf8(const __hip_bfloat16* p) {
  int4 v = *reinterpret_cast<const int4*>(p);
  return __builtin_bit_cast(bf16x8, v);
}

// ---------------- K1: hs[r][o] = (x[r][:] @ gcn_W[:,o]) * dinv[r>>3], bf16 ----------------
__global__ __launch_bounds__(256) void k_transform(const float* __restrict__ x,
                                                   const float* __restrict__ W,
                                                   const float* __restrict__ dinv,
                                                   __hip_bfloat16* __restrict__ hs)
{
  __shared__ float Ws[F_IN * H_GCN];
  __shared__ float xs[8][F_IN];
  int tid = threadIdx.x;
  for (int i = tid; i < F_IN * H_GCN; i += 256) Ws[i] = W[i];
  long r0 = (long)blockIdx.x * 8;
  int idx = tid * 4;
  float4 xv = *reinterpret_cast<const float4*>(x + r0 * F_IN + idx);
  int rl = idx >> 7, c0 = idx & 127;
  xs[rl][c0] = xv.x; xs[rl][c0 + 1] = xv.y; xs[rl][c0 + 2] = xv.z; xs[rl][c0 + 3] = xv.w;
  __syncthreads();
  int rr = tid >> 5, o = tid & 31;
  float acc = 0.f;
  #pragma unroll 8
  for (int f = 0; f < F_IN; f += 4) {
    float4 x4 = *reinterpret_cast<const float4*>(&xs[rr][f]);
    acc = fmaf(x4.x, Ws[(f + 0) * H_GCN + o], acc);
    acc = fmaf(x4.y, Ws[(f + 1) * H_GCN + o], acc);
    acc = fmaf(x4.z, Ws[(f + 2) * H_GCN + o], acc);
    acc = fmaf(x4.w, Ws[(f + 3) * H_GCN + o], acc);
  }
  long r = r0 + rr;
  hs[r * H_GCN + o] = __float2bfloat16(acc * dinv[r >> 3]);
}

// ---------------- K2: in-degree count ----------------
__global__ void k_count(const int* __restrict__ col, int* __restrict__ cnt, int E)
{
  int i = blockIdx.x * 256 + threadIdx.x;
  if (i < E) atomicAdd(&cnt[col[i]], 1);
}

// ---------------- K2b: fill padded adjacency with dummy node N ----------------
__global__ void k_adj_init(int* __restrict__ adj, int N, int padE)
{
  int i = blockIdx.x * 1024 + threadIdx.x;
  if (i < padE) adj[i] = N;
}

// ---------------- K3: scan over PADDED counts -> row_ptr (padded bases), cursor, dinv ----------------
__global__ __launch_bounds__(1024) void k_scan(const int* __restrict__ cnt,
                                               int* __restrict__ row_ptr,
                                               int* __restrict__ cursor,
                                               float* __restrict__ dinv, int N)
{
  __shared__ int s[1024];
  int tid = threadIdx.x;
  const int CH = (N + 1023) >> 10;
  int i0 = tid * CH;
  int sum = 0;
  for (int j = 0; j < CH; ++j) {
    int i = i0 + j;
    if (i < N) sum += (cnt[i] + 7) & ~7;
  }
  s[tid] = sum;
  __syncthreads();
  #pragma unroll
  for (int off = 1; off < 1024; off <<= 1) {
    int t = (tid >= off) ? s[tid - off] : 0;
    __syncthreads();
    s[tid] += t;
    __syncthreads();
  }
  int run = (tid > 0) ? s[tid - 1] : 0;
  for (int j = 0; j < CH; ++j) {
    int i = i0 + j;
    if (i < N) {
      int v = cnt[i];
      cursor[i] = run;
      row_ptr[i] = run;
      dinv[i] = rsqrtf((float)v + 1.0f);
      run += (v + 7) & ~7;
      if (i == N - 1) row_ptr[N] = run;
    }
  }
}

// ---------------- K4: fill adjacency ----------------
__global__ void k_fill(const int* __restrict__ ei, int* __restrict__ cursor,
                       int* __restrict__ adj, int E)
{
  int e = blockIdx.x * 256 + threadIdx.x;
  if (e < E) {
    int r = ei[e], c = ei[E + e];
    int pos = atomicAdd(&cursor[c], 1);
    adj[pos] = r;
  }
}

// ---------------- K5: fused gather + relu + Conv1d + relu ----------------
// 4 nodes/block, one wave per node; adjacency padded to x8 -> branch-free
// 8-deep explicit load pipeline (named regs). Single dependent level:
// adj (uniform s_load) -> row (8B/lane). dinv pre-folded into hs.
__global__ __launch_bounds__(256) void k_gather_conv(
    const int* __restrict__ row_ptr, const int* __restrict__ adj,
    const float* __restrict__ dinv, const __hip_bfloat16* __restrict__ hs,
    const float* __restrict__ gcnb,
    const float* __restrict__ Wc, const float* __restrict__ bc,
    __hip_bfloat16* __restrict__ seq, int N)
{
  __shared__ float Ws[64 * 65];   // transposed conv weights: [(ci*2+k)*65 + co]
  __shared__ float gs[4][8][33];  // [node][t][ci]
  int tid  = threadIdx.x;
  int wave = tid >> 6;
  int lane = tid & 63;

  for (int i = tid; i < 64 * 64; i += 256) {
    int co = i >> 6, ci2 = i & 63;
    Ws[ci2 * 65 + co] = Wc[i];
  }

  int n = blockIdx.x * 4 + wave;
  int start = row_ptr[n], end = row_ptr[n + 1];
  float dn = dinv[n];

  const __hip_bfloat16* hl = hs + lane * 4;   // per-lane column base
  float acc0, acc1, acc2, acc3;
  {
    ushort4 hv = *reinterpret_cast<const ushort4*>(hl + (size_t)n * 256);
    acc0 = ubf(hv.x); acc1 = ubf(hv.y); acc2 = ubf(hv.z); acc3 = ubf(hv.w);
  }

  for (int base = start; base < end; base += 8) {
    int s0 = adj[base + 0], s1 = adj[base + 1], s2 = adj[base + 2], s3 = adj[base + 3];
    int s4 = adj[base + 4], s5 = adj[base + 5], s6 = adj[base + 6], s7 = adj[base + 7];
    ushort4 r0 = *reinterpret_cast<const ushort4*>(hl + (size_t)s0 * 256);
    ushort4 r1 = *reinterpret_cast<const ushort4*>(hl + (size_t)s1 * 256);
    ushort4 r2 = *reinterpret_cast<const ushort4*>(hl + (size_t)s2 * 256);
    ushort4 r3 = *reinterpret_cast<const ushort4*>(hl + (size_t)s3 * 256);
    ushort4 r4 = *reinterpret_cast<const ushort4*>(hl + (size_t)s4 * 256);
    ushort4 r5 = *reinterpret_cast<const ushort4*>(hl + (size_t)s5 * 256);
    ushort4 r6 = *reinterpret_cast<const ushort4*>(hl + (size_t)s6 * 256);
    ushort4 r7 = *reinterpret_cast<const ushort4*>(hl + (size_t)s7 * 256);
    acc0 += ubf(r0.x) + ubf(r1.x) + ubf(r2.x) + ubf(r3.x) + ubf(r4.x) + ubf(r5.x) + ubf(r6.x) + ubf(r7.x);
    acc1 += ubf(r0.y) + ubf(r1.y) + ubf(r2.y) + ubf(r3.y) + ubf(r4.y) + ubf(r5.y) + ubf(r6.y) + ubf(r7.y);
    acc2 += ubf(r0.z) + ubf(r1.z) + ubf(r2.z) + ubf(r3.z) + ubf(r4.z) + ubf(r5.z) + ubf(r6.z) + ubf(r7.z);
    acc3 += ubf(r0.w) + ubf(r1.w) + ubf(r2.w) + ubf(r3.w) + ubf(r4.w) + ubf(r5.w) + ubf(r6.w) + ubf(r7.w);
  }

  int col0 = lane * 4;             // 4-aligned: all 4 cols share t
  int t0 = col0 >> 5, ci0 = col0 & 31;
  gs[wave][t0][ci0 + 0] = fmaxf(fmaf(acc0, dn, gcnb[ci0 + 0]), 0.f);
  gs[wave][t0][ci0 + 1] = fmaxf(fmaf(acc1, dn, gcnb[ci0 + 1]), 0.f);
  gs[wave][t0][ci0 + 2] = fmaxf(fmaf(acc2, dn, gcnb[ci0 + 2]), 0.f);
  gs[wave][t0][ci0 + 3] = fmaxf(fmaf(acc3, dn, gcnb[ci0 + 3]), 0.f);
  __syncthreads();

  // conv: 4 nodes x 7 t x 64 co = 1792 outputs = 7 per thread
  long n64 = (long)N * 64;
  #pragma unroll
  for (int rep = 0; rep < 7; ++rep) {
    int p = rep * 256 + tid;
    int nl = p / 448;
    int q  = p - nl * 448;
    int t = q >> 6, co = q & 63;
    float o = bc[co];
    #pragma unroll
    for (int ci = 0; ci < 32; ++ci) {
      o = fmaf(gs[nl][t][ci],     Ws[(ci * 2)     * 65 + co], o);
      o = fmaf(gs[nl][t + 1][ci], Ws[(ci * 2 + 1) * 65 + co], o);
    }
    int nn = blockIdx.x * 4 + nl;
    seq[(long)t * n64 + (long)nn * 64 + co] = __float2bfloat16(fmaxf(o, 0.f));
  }
}

// ---------------- K6: pack bf16 weights (parallel elementwise) ----------------
__global__ __launch_bounds__(256) void k_prep(const float* __restrict__ Wih, const float* __restrict__ Whh,
                       const float* __restrict__ bih, const float* __restrict__ bhh,
                       const float* __restrict__ fc1W, const float* __restrict__ fc2W,
                       __hip_bfloat16* __restrict__ Wcat, float* __restrict__ bias,
                       __hip_bfloat16* __restrict__ W1b, __hip_bfloat16* __restrict__ W2b)
{
  int i = blockIdx.x * 256 + threadIdx.x;
  if (i < 512 * 192) {
    int q = i / 192, k = i - q * 192;
    float v = (k < 64) ? Wih[q * 64 + k] : Whh[q * 128 + (k - 64)];
    Wcat[i] = __float2bfloat16(v);
  } else if (i < 512 * 192 + 64 * 128) {
    int j = i - 512 * 192;
    W1b[j] = __float2bfloat16(fc1W[j]);
  } else if (i < 512 * 192 + 64 * 128 + 128 * 64) {
    int j = i - 512 * 192 - 64 * 128;
    W2b[j] = __float2bfloat16(fc2W[j]);
  } else if (i < 512 * 192 + 64 * 128 + 128 * 64 + 512) {
    int j = i - 512 * 192 - 64 * 128 - 128 * 64;
    bias[j] = bih[j] + bhh[j];
  }
}

// ---------------- K7: fused 7-step LSTM + head ----------------
__global__ __launch_bounds__(512) void k_lstm_head(
    const __hip_bfloat16* __restrict__ seq,   // [7][N][64]
    const __hip_bfloat16* __restrict__ Wcat,  // [512][192]
    const float* __restrict__ bias,           // [512]
    const __hip_bfloat16* __restrict__ W1b,   // [64][128]
    const float* __restrict__ fc1b,
    const __hip_bfloat16* __restrict__ W2b,   // [128][64]
    const float* __restrict__ fc2b,
    float* __restrict__ out, int N)
{
  __shared__ __hip_bfloat16 h_lds[16][136];
  __shared__ __hip_bfloat16 s1_lds[16][72];
  int tid  = threadIdx.x;
  int wave = tid >> 6;
  int lane = tid & 63;
  int l15  = lane & 15;
  int lhi  = lane >> 4;
  long n0  = (long)blockIdx.x * 16;
  int hc   = wave * 16 + l15;

  // hoist all B fragments for this wave's 64 Wcat rows into registers
  bf16x8 bw[6][4];
  #pragma unroll
  for (int ks = 0; ks < 6; ++ks)
    #pragma unroll
    for (int gg = 0; gg < 4; ++gg)
      bw[ks][gg] = load_bf8(Wcat + (size_t)(gg * 128 + hc) * 192 + ks * 32 + lhi * 8);

  float bi = bias[hc], bff = bias[128 + hc], bg = bias[256 + hc], bo = bias[384 + hc];
  float c[4] = {0.f, 0.f, 0.f, 0.f};

  const __hip_bfloat16* sp = seq + (n0 + l15) * 64 + lhi * 8;
  size_t tstr = (size_t)N * 64;
  bf16x8 ax0 = load_bf8(sp);
  bf16x8 ax1 = load_bf8(sp + 32);

  for (int t = 0; t < 7; ++t) {
    bf16x8 nx0, nx1;
    if (t < 6) {                      // prefetch next step's A
      nx0 = load_bf8(sp + (size_t)(t + 1) * tstr);
      nx1 = load_bf8(sp + (size_t)(t + 1) * tstr + 32);
    }
    f32x4 acc[4];
    #pragma unroll
    for (int gg = 0; gg < 4; ++gg) acc[gg] = (f32x4){0.f, 0.f, 0.f, 0.f};

    #pragma unroll
    for (int gg = 0; gg < 4; ++gg)
      acc[gg] = __builtin_amdgcn_mfma_f32_16x16x32_bf16(ax0, bw[0][gg], acc[gg], 0, 0, 0);
    #pragma unroll
    for (int gg = 0; gg < 4; ++gg)
      acc[gg] = __builtin_amdgcn_mfma_f32_16x16x32_bf16(ax1, bw[1][gg], acc[gg], 0, 0, 0);

    if (t > 0) {
      #pragma unroll
      for (int ks = 2; ks < 6; ++ks) {
        bf16x8 a = load_bf8(&h_lds[l15][(ks - 2) * 32 + lhi * 8]);
        #pragma unroll
        for (int gg = 0; gg < 4; ++gg)
          acc[gg] = __builtin_amdgcn_mfma_f32_16x16x32_bf16(a, bw[ks][gg], acc[gg], 0, 0, 0);
      }
    }
    __syncthreads();   // h_lds reads done before overwrite

    #pragma unroll
    for (int r = 0; r < 4; ++r) {
      float zi = acc[0][r] + bi;
      float zf = acc[1][r] + bff;
      float zg = acc[2][r] + bg;
      float zo = acc[3][r] + bo;
      float cn = sigm(zf) * c[r] + sigm(zi) * tanh_f(zg);
      c[r] = cn;
      h_lds[lhi * 4 + r][hc] = __float2bfloat16(sigm(zo) * tanh_f(cn));
    }
    __syncthreads();   // h_lds visible for next step

    ax0 = nx0; ax1 = nx1;
  }

  // ---- head stage 1: s1[16][64] = relu(h @ W1^T + b1), waves 0-3 ----
  if (wave < 4) {
    int col1 = wave * 16 + l15;
    f32x4 acc1 = (f32x4){0.f, 0.f, 0.f, 0.f};
    #pragma unroll
    for (int ks = 0; ks < 4; ++ks) {
      int kb = ks * 32 + lhi * 8;
      bf16x8 a = load_bf8(&h_lds[l15][kb]);
      bf16x8 b = load_bf8(W1b + col1 * 128 + kb);
      acc1 = __builtin_amdgcn_mfma_f32_16x16x32_bf16(a, b, acc1, 0, 0, 0);
    }
    float b1 = fc1b[col1];
    #pragma unroll
    for (int r = 0; r < 4; ++r)
      s1_lds[lhi * 4 + r][col1] = __float2bfloat16(fmaxf(acc1[r] + b1, 0.f));
  }
  __syncthreads();

  // ---- head stage 2: out[16][128] = sigmoid(s1 @ W2^T + b2), all 8 waves ----
  {
    int c2 = wave * 16 + l15;
    f32x4 acc2 = (f32x4){0.f, 0.f, 0.f, 0.f};
    #pragma unroll
    for (int ks = 0; ks < 2; ++ks) {
      int kb = ks * 32 + lhi * 8;
      bf16x8 a = load_bf8(&s1_lds[l15][kb]);
      bf16x8 b = load_bf8(W2b + c2 * 64 + kb);
      acc2 = __builtin_amdgcn_mfma_f32_16x16x32_bf16(a, b, acc2, 0, 0, 0);
    }
    float b2 = fc2b[c2];
    #pragma unroll
    for (int r = 0; r < 4; ++r)
      out[(n0 + lhi * 4 + r) * 128 + c2] = sigm(acc2[r] + b2);
  }
}

extern "C" void kernel_launch(void* const* d_in, const int* in_sizes, int n_in,
                              void* d_out, int out_size, void* d_ws, size_t ws_size,
                              hipStream_t stream)
{
  const float* x     = (const float*)d_in[0];
  const int*   ei    = (const int*)d_in[1];
  const float* gcnW  = (const float*)d_in[2];
  const float* gcnb  = (const float*)d_in[3];
  const float* convW = (const float*)d_in[4];
  const float* convb = (const float*)d_in[5];
  const float* Wih   = (const float*)d_in[6];
  const float* Whh   = (const float*)d_in[7];
  const float* bih   = (const float*)d_in[8];
  const float* bhh   = (const float*)d_in[9];
  const float* fc1W  = (const float*)d_in[10];
  const float* fc1b  = (const float*)d_in[11];
  const float* fc2W  = (const float*)d_in[12];
  const float* fc2b  = (const float*)d_in[13];

  const int N = in_sizes[0] / (T_STEPS * F_IN);
  const int E = in_sizes[1] / 2;
  const int padE = E + 8 * N;   // worst-case padded adjacency size

  char* ws = (char*)d_ws;
  size_t off = 0;
  auto alloc = [&](size_t bytes) {
    void* p = ws + off;
    off = (off + bytes + 255) & ~(size_t)255;
    return p;
  };
  __hip_bfloat16* hs  = (__hip_bfloat16*)alloc((size_t)(N + 1) * 256 * 2); // [N+1][256], row N = zeros
  __hip_bfloat16* seq = (__hip_bfloat16*)alloc((size_t)7 * N * 64 * 2);    // [7][N][64]
  int* cnt     = (int*)alloc((size_t)N * 4);
  int* row_ptr = (int*)alloc((size_t)(N + 1) * 4);
  int* cursor  = (int*)alloc((size_t)N * 4);
  float* dinv  = (float*)alloc((size_t)N * 4);
  int* adj     = (int*)alloc((size_t)padE * 4);
  __hip_bfloat16* Wcat = (__hip_bfloat16*)alloc(512 * 192 * 2);
  float* bias = (float*)alloc(512 * 4);
  __hip_bfloat16* W1b = (__hip_bfloat16*)alloc(64 * 128 * 2);
  __hip_bfloat16* W2b = (__hip_bfloat16*)alloc(128 * 64 * 2);

  hipMemsetAsync(cnt, 0, (size_t)N * 4, stream);
  hipMemsetAsync(hs + (size_t)N * 256, 0, 256 * 2, stream);   // dummy zero row

  const int PREP_TOT = 512 * 192 + 64 * 128 + 128 * 64 + 512;
  k_prep<<<(PREP_TOT + 255) / 256, 256, 0, stream>>>(Wih, Whh, bih, bhh, fc1W, fc2W, Wcat, bias, W1b, W2b);
  k_count<<<(E + 255) / 256, 256, 0, stream>>>(ei + E, cnt, E);
  k_adj_init<<<(padE + 1023) / 1024, 1024, 0, stream>>>(adj, N, padE);
  k_scan<<<1, 1024, 0, stream>>>(cnt, row_ptr, cursor, dinv, N);
  k_transform<<<(N * T_STEPS) / 8, 256, 0, stream>>>(x, gcnW, dinv, hs);
  k_fill<<<(E + 255) / 256, 256, 0, stream>>>(ei, cursor, adj, E);
  k_gather_conv<<<N / 4, 256, 0, stream>>>(row_ptr, adj, dinv, hs, gcnb, convW, convb, seq, N);
  k_lstm_head<<<N / 16, 512, 0, stream>>>(seq, Wcat, bias, W1b, fc1b, W2b, fc2b, (float*)d_out, N);
}

// Round 7
// 336.237 us; speedup vs baseline: 2.3536x; 1.0449x over previous
//
#include <hip/hip_runtime.h>
#include <hip/hip_bf16.h>

#define T_STEPS 8
#define F_IN    128
#define H_GCN   32
#define H_CONV  64
#define H_LSTM  128

typedef __bf16 bf16x8 __attribute__((ext_vector_type(8)));
typedef float  f32x4  __attribute__((ext_vector_type(4)));

__device__ __forceinline__ float sigm(float x)   { return 1.f / (1.f + __expf(-x)); }
__device__ __forceinline__ float tanh_f(float x) { return 1.f - 2.f / (__expf(2.f * x) + 1.f); }

__device__ __forceinline__ float ubf(unsigned short u) {
  union { unsigned int i; float f; } v; v.i = ((unsigned int)u) << 16; return v.f;
}

__device__ __forceinline__ bf16x8 load_bf8(const __hip_bfloat16* p) {
  int4 v = *reinterpret_cast<const int4*>(p);
  return __builtin_bit_cast(bf16x8, v);
}

// ---------------- K1: hs[r][o] = (x[r][:] @ gcn_W[:,o]) * dinv[r>>3], bf16 ----------------
__global__ __launch_bounds__(256) void k_transform(const float* __restrict__ x,
                                                   const float* __restrict__ W,
                                                   const float* __restrict__ dinv,
                                                   __hip_bfloat16* __restrict__ hs)
{
  __shared__ float Ws[F_IN * H_GCN];
  __shared__ float xs[8][F_IN];
  int tid = threadIdx.x;
  for (int i = tid; i < F_IN * H_GCN; i += 256) Ws[i] = W[i];
  long r0 = (long)blockIdx.x * 8;
  int idx = tid * 4;
  float4 xv = *reinterpret_cast<const float4*>(x + r0 * F_IN + idx);
  int rl = idx >> 7, c0 = idx & 127;
  xs[rl][c0] = xv.x; xs[rl][c0 + 1] = xv.y; xs[rl][c0 + 2] = xv.z; xs[rl][c0 + 3] = xv.w;
  __syncthreads();
  int rr = tid >> 5, o = tid & 31;
  float acc = 0.f;
  #pragma unroll 8
  for (int f = 0; f < F_IN; f += 4) {
    float4 x4 = *reinterpret_cast<const float4*>(&xs[rr][f]);
    acc = fmaf(x4.x, Ws[(f + 0) * H_GCN + o], acc);
    acc = fmaf(x4.y, Ws[(f + 1) * H_GCN + o], acc);
    acc = fmaf(x4.z, Ws[(f + 2) * H_GCN + o], acc);
    acc = fmaf(x4.w, Ws[(f + 3) * H_GCN + o], acc);
  }
  long r = r0 + rr;
  hs[r * H_GCN + o] = __float2bfloat16(acc * dinv[r >> 3]);
}

// ---------------- K2: in-degree count ----------------
__global__ void k_count(const int* __restrict__ col, int* __restrict__ cnt, int E)
{
  int i = blockIdx.x * 256 + threadIdx.x;
  if (i < E) atomicAdd(&cnt[col[i]], 1);
}

// ---------------- K2b: fill padded adjacency with dummy node N ----------------
__global__ void k_adj_init(int* __restrict__ adj, int N, int padE)
{
  int i = blockIdx.x * 1024 + threadIdx.x;
  if (i < padE) adj[i] = N;
}

// ---------------- K3: scan over PADDED counts -> row_ptr (padded bases), cursor, dinv ----------------
__global__ __launch_bounds__(1024) void k_scan(const int* __restrict__ cnt,
                                               int* __restrict__ row_ptr,
                                               int* __restrict__ cursor,
                                               float* __restrict__ dinv, int N)
{
  __shared__ int s[1024];
  int tid = threadIdx.x;
  const int CH = (N + 1023) >> 10;
  int i0 = tid * CH;
  int sum = 0;
  for (int j = 0; j < CH; ++j) {
    int i = i0 + j;
    if (i < N) sum += (cnt[i] + 7) & ~7;
  }
  s[tid] = sum;
  __syncthreads();
  #pragma unroll
  for (int off = 1; off < 1024; off <<= 1) {
    int t = (tid >= off) ? s[tid - off] : 0;
    __syncthreads();
    s[tid] += t;
    __syncthreads();
  }
  int run = (tid > 0) ? s[tid - 1] : 0;
  for (int j = 0; j < CH; ++j) {
    int i = i0 + j;
    if (i < N) {
      int v = cnt[i];
      cursor[i] = run;
      row_ptr[i] = run;
      dinv[i] = rsqrtf((float)v + 1.0f);
      run += (v + 7) & ~7;
      if (i == N - 1) row_ptr[N] = run;
    }
  }
}

// ---------------- K4: fill adjacency ----------------
__global__ void k_fill(const int* __restrict__ ei, int* __restrict__ cursor,
                       int* __restrict__ adj, int E)
{
  int e = blockIdx.x * 256 + threadIdx.x;
  if (e < E) {
    int r = ei[e], c = ei[E + e];
    int pos = atomicAdd(&cursor[c], 1);
    adj[pos] = r;
  }
}

// ---------------- K5: fused gather + relu + Conv1d + relu ----------------
// 4 nodes/block, one wave per node; adjacency padded to x8 -> branch-free
// 8-deep explicit load pipeline. dinv pre-folded into hs.
__global__ __launch_bounds__(256) void k_gather_conv(
    const int* __restrict__ row_ptr, const int* __restrict__ adj,
    const float* __restrict__ dinv, const __hip_bfloat16* __restrict__ hs,
    const float* __restrict__ gcnb,
    const float* __restrict__ Wc, const float* __restrict__ bc,
    __hip_bfloat16* __restrict__ seq, int N)
{
  __shared__ float Ws[64 * 65];   // transposed conv weights: [(ci*2+k)*65 + co]
  __shared__ float gs[4][8][33];  // [node][t][ci]
  int tid  = threadIdx.x;
  int wave = tid >> 6;
  int lane = tid & 63;

  for (int i = tid; i < 64 * 64; i += 256) {
    int co = i >> 6, ci2 = i & 63;
    Ws[ci2 * 65 + co] = Wc[i];
  }

  int n = blockIdx.x * 4 + wave;
  int start = row_ptr[n], end = row_ptr[n + 1];
  float dn = dinv[n];

  const __hip_bfloat16* hl = hs + lane * 4;   // per-lane column base
  float acc0, acc1, acc2, acc3;
  {
    ushort4 hv = *reinterpret_cast<const ushort4*>(hl + (size_t)n * 256);
    acc0 = ubf(hv.x); acc1 = ubf(hv.y); acc2 = ubf(hv.z); acc3 = ubf(hv.w);
  }

  for (int base = start; base < end; base += 8) {
    int s0 = adj[base + 0], s1 = adj[base + 1], s2 = adj[base + 2], s3 = adj[base + 3];
    int s4 = adj[base + 4], s5 = adj[base + 5], s6 = adj[base + 6], s7 = adj[base + 7];
    ushort4 r0 = *reinterpret_cast<const ushort4*>(hl + (size_t)s0 * 256);
    ushort4 r1 = *reinterpret_cast<const ushort4*>(hl + (size_t)s1 * 256);
    ushort4 r2 = *reinterpret_cast<const ushort4*>(hl + (size_t)s2 * 256);
    ushort4 r3 = *reinterpret_cast<const ushort4*>(hl + (size_t)s3 * 256);
    ushort4 r4 = *reinterpret_cast<const ushort4*>(hl + (size_t)s4 * 256);
    ushort4 r5 = *reinterpret_cast<const ushort4*>(hl + (size_t)s5 * 256);
    ushort4 r6 = *reinterpret_cast<const ushort4*>(hl + (size_t)s6 * 256);
    ushort4 r7 = *reinterpret_cast<const ushort4*>(hl + (size_t)s7 * 256);
    acc0 += ubf(r0.x) + ubf(r1.x) + ubf(r2.x) + ubf(r3.x) + ubf(r4.x) + ubf(r5.x) + ubf(r6.x) + ubf(r7.x);
    acc1 += ubf(r0.y) + ubf(r1.y) + ubf(r2.y) + ubf(r3.y) + ubf(r4.y) + ubf(r5.y) + ubf(r6.y) + ubf(r7.y);
    acc2 += ubf(r0.z) + ubf(r1.z) + ubf(r2.z) + ubf(r3.z) + ubf(r4.z) + ubf(r5.z) + ubf(r6.z) + ubf(r7.z);
    acc3 += ubf(r0.w) + ubf(r1.w) + ubf(r2.w) + ubf(r3.w) + ubf(r4.w) + ubf(r5.w) + ubf(r6.w) + ubf(r7.w);
  }

  int col0 = lane * 4;
  int t0 = col0 >> 5, ci0 = col0 & 31;
  gs[wave][t0][ci0 + 0] = fmaxf(fmaf(acc0, dn, gcnb[ci0 + 0]), 0.f);
  gs[wave][t0][ci0 + 1] = fmaxf(fmaf(acc1, dn, gcnb[ci0 + 1]), 0.f);
  gs[wave][t0][ci0 + 2] = fmaxf(fmaf(acc2, dn, gcnb[ci0 + 2]), 0.f);
  gs[wave][t0][ci0 + 3] = fmaxf(fmaf(acc3, dn, gcnb[ci0 + 3]), 0.f);
  __syncthreads();

  long n64 = (long)N * 64;
  #pragma unroll
  for (int rep = 0; rep < 7; ++rep) {
    int p = rep * 256 + tid;
    int nl = p / 448;
    int q  = p - nl * 448;
    int t = q >> 6, co = q & 63;
    float o = bc[co];
    #pragma unroll
    for (int ci = 0; ci < 32; ++ci) {
      o = fmaf(gs[nl][t][ci],     Ws[(ci * 2)     * 65 + co], o);
      o = fmaf(gs[nl][t + 1][ci], Ws[(ci * 2 + 1) * 65 + co], o);
    }
    int nn = blockIdx.x * 4 + nl;
    seq[(long)t * n64 + (long)nn * 64 + co] = __float2bfloat16(fmaxf(o, 0.f));
  }
}

// ---------------- K6: pack bf16 weights (parallel elementwise) ----------------
__global__ __launch_bounds__(256) void k_prep(const float* __restrict__ Wih, const float* __restrict__ Whh,
                       const float* __restrict__ bih, const float* __restrict__ bhh,
                       const float* __restrict__ fc1W, const float* __restrict__ fc2W,
                       __hip_bfloat16* __restrict__ Wcat, float* __restrict__ bias,
                       __hip_bfloat16* __restrict__ W1b, __hip_bfloat16* __restrict__ W2b)
{
  int i = blockIdx.x * 256 + threadIdx.x;
  if (i < 512 * 192) {
    int q = i / 192, k = i - q * 192;
    float v = (k < 64) ? Wih[q * 64 + k] : Whh[q * 128 + (k - 64)];
    Wcat[i] = __float2bfloat16(v);
  } else if (i < 512 * 192 + 64 * 128) {
    int j = i - 512 * 192;
    W1b[j] = __float2bfloat16(fc1W[j]);
  } else if (i < 512 * 192 + 64 * 128 + 128 * 64) {
    int j = i - 512 * 192 - 64 * 128;
    W2b[j] = __float2bfloat16(fc2W[j]);
  } else if (i < 512 * 192 + 64 * 128 + 128 * 64 + 512) {
    int j = i - 512 * 192 - 64 * 128 - 128 * 64;
    bias[j] = bih[j] + bhh[j];
  }
}

// ---------------- K7: fused 7-step LSTM + head ----------------
// 512 threads = 8 waves, launch_bounds(512,2) -> 256 VGPR budget so all 24
// B-fragments (96 VGPR) stay register-resident across the whole t-loop.
// Double-buffered h_lds -> ONE barrier per step.
__global__ __launch_bounds__(512, 2) void k_lstm_head(
    const __hip_bfloat16* __restrict__ seq,   // [7][N][64]
    const __hip_bfloat16* __restrict__ Wcat,  // [512][192]
    const float* __restrict__ bias,           // [512]
    const __hip_bfloat16* __restrict__ W1b,   // [64][128]
    const float* __restrict__ fc1b,
    const __hip_bfloat16* __restrict__ W2b,   // [128][64]
    const float* __restrict__ fc2b,
    float* __restrict__ out, int N)
{
  __shared__ __hip_bfloat16 h_lds[2][16][136];  // double buffer: write t&1, read (t+1)&1
  __shared__ __hip_bfloat16 s1_lds[16][72];
  int tid  = threadIdx.x;
  int wave = tid >> 6;
  int lane = tid & 63;
  int l15  = lane & 15;
  int lhi  = lane >> 4;
  long n0  = (long)blockIdx.x * 16;
  int hc   = wave * 16 + l15;

  // hoist all B fragments for this wave's 64 Wcat rows into registers (96 VGPR)
  bf16x8 bw[6][4];
  #pragma unroll
  for (int ks = 0; ks < 6; ++ks)
    #pragma unroll
    for (int gg = 0; gg < 4; ++gg)
      bw[ks][gg] = load_bf8(Wcat + (size_t)(gg * 128 + hc) * 192 + ks * 32 + lhi * 8);

  float bi = bias[hc], bff = bias[128 + hc], bg = bias[256 + hc], bo = bias[384 + hc];
  float c[4] = {0.f, 0.f, 0.f, 0.f};

  const __hip_bfloat16* sp = seq + (n0 + l15) * 64 + lhi * 8;
  size_t tstr = (size_t)N * 64;
  bf16x8 ax0 = load_bf8(sp);
  bf16x8 ax1 = load_bf8(sp + 32);

  for (int t = 0; t < 7; ++t) {
    bf16x8 nx0, nx1;
    if (t < 6) {                      // prefetch next step's A
      nx0 = load_bf8(sp + (size_t)(t + 1) * tstr);
      nx1 = load_bf8(sp + (size_t)(t + 1) * tstr + 32);
    }
    f32x4 acc[4];
    #pragma unroll
    for (int gg = 0; gg < 4; ++gg) acc[gg] = (f32x4){0.f, 0.f, 0.f, 0.f};

    #pragma unroll
    for (int gg = 0; gg < 4; ++gg)
      acc[gg] = __builtin_amdgcn_mfma_f32_16x16x32_bf16(ax0, bw[0][gg], acc[gg], 0, 0, 0);
    #pragma unroll
    for (int gg = 0; gg < 4; ++gg)
      acc[gg] = __builtin_amdgcn_mfma_f32_16x16x32_bf16(ax1, bw[1][gg], acc[gg], 0, 0, 0);

    if (t > 0) {
      const __hip_bfloat16* hb = &h_lds[(t + 1) & 1][0][0];
      #pragma unroll
      for (int ks = 2; ks < 6; ++ks) {
        bf16x8 a = load_bf8(hb + l15 * 136 + (ks - 2) * 32 + lhi * 8);
        #pragma unroll
        for (int gg = 0; gg < 4; ++gg)
          acc[gg] = __builtin_amdgcn_mfma_f32_16x16x32_bf16(a, bw[ks][gg], acc[gg], 0, 0, 0);
      }
    }

    __hip_bfloat16* hw = &h_lds[t & 1][0][0];
    #pragma unroll
    for (int r = 0; r < 4; ++r) {
      float zi = acc[0][r] + bi;
      float zf = acc[1][r] + bff;
      float zg = acc[2][r] + bg;
      float zo = acc[3][r] + bo;
      float cn = sigm(zf) * c[r] + sigm(zi) * tanh_f(zg);
      c[r] = cn;
      hw[(lhi * 4 + r) * 136 + hc] = __float2bfloat16(sigm(zo) * tanh_f(cn));
    }
    __syncthreads();   // write buffer visible; read buffer free for overwrite next step

    ax0 = nx0; ax1 = nx1;
  }

  // ---- head stage 1: s1[16][64] = relu(h @ W1^T + b1), waves 0-3 ----
  // last write (t=6) went to h_lds[0]
  if (wave < 4) {
    int col1 = wave * 16 + l15;
    f32x4 acc1 = (f32x4){0.f, 0.f, 0.f, 0.f};
    #pragma unroll
    for (int ks = 0; ks < 4; ++ks) {
      int kb = ks * 32 + lhi * 8;
      bf16x8 a = load_bf8(&h_lds[0][l15][kb]);
      bf16x8 b = load_bf8(W1b + col1 * 128 + kb);
      acc1 = __builtin_amdgcn_mfma_f32_16x16x32_bf16(a, b, acc1, 0, 0, 0);
    }
    float b1 = fc1b[col1];
    #pragma unroll
    for (int r = 0; r < 4; ++r)
      s1_lds[lhi * 4 + r][col1] = __float2bfloat16(fmaxf(acc1[r] + b1, 0.f));
  }
  __syncthreads();

  // ---- head stage 2: out[16][128] = sigmoid(s1 @ W2^T + b2), all 8 waves ----
  {
    int c2 = wave * 16 + l15;
    f32x4 acc2 = (f32x4){0.f, 0.f, 0.f, 0.f};
    #pragma unroll
    for (int ks = 0; ks < 2; ++ks) {
      int kb = ks * 32 + lhi * 8;
      bf16x8 a = load_bf8(&s1_lds[l15][kb]);
      bf16x8 b = load_bf8(W2b + c2 * 64 + kb);
      acc2 = __builtin_amdgcn_mfma_f32_16x16x32_bf16(a, b, acc2, 0, 0, 0);
    }
    float b2 = fc2b[c2];
    #pragma unroll
    for (int r = 0; r < 4; ++r)
      out[(n0 + lhi * 4 + r) * 128 + c2] = sigm(acc2[r] + b2);
  }
}

extern "C" void kernel_launch(void* const* d_in, const int* in_sizes, int n_in,
                              void* d_out, int out_size, void* d_ws, size_t ws_size,
                              hipStream_t stream)
{
  const float* x     = (const float*)d_in[0];
  const int*   ei    = (const int*)d_in[1];
  const float* gcnW  = (const float*)d_in[2];
  const float* gcnb  = (const float*)d_in[3];
  const float* convW = (const float*)d_in[4];
  const float* convb = (const float*)d_in[5];
  const float* Wih   = (const float*)d_in[6];
  const float* Whh   = (const float*)d_in[7];
  const float* bih   = (const float*)d_in[8];
  const float* bhh   = (const float*)d_in[9];
  const float* fc1W  = (const float*)d_in[10];
  const float* fc1b  = (const float*)d_in[11];
  const float* fc2W  = (const float*)d_in[12];
  const float* fc2b  = (const float*)d_in[13];

  const int N = in_sizes[0] / (T_STEPS * F_IN);
  const int E = in_sizes[1] / 2;
  const int padE = E + 8 * N;

  char* ws = (char*)d_ws;
  size_t off = 0;
  auto alloc = [&](size_t bytes) {
    void* p = ws + off;
    off = (off + bytes + 255) & ~(size_t)255;
    return p;
  };
  __hip_bfloat16* hs  = (__hip_bfloat16*)alloc((size_t)(N + 1) * 256 * 2); // [N+1][256], row N = zeros
  __hip_bfloat16* seq = (__hip_bfloat16*)alloc((size_t)7 * N * 64 * 2);    // [7][N][64]
  int* cnt     = (int*)alloc((size_t)N * 4);
  int* row_ptr = (int*)alloc((size_t)(N + 1) * 4);
  int* cursor  = (int*)alloc((size_t)N * 4);
  float* dinv  = (float*)alloc((size_t)N * 4);
  int* adj     = (int*)alloc((size_t)padE * 4);
  __hip_bfloat16* Wcat = (__hip_bfloat16*)alloc(512 * 192 * 2);
  float* bias = (float*)alloc(512 * 4);
  __hip_bfloat16* W1b = (__hip_bfloat16*)alloc(64 * 128 * 2);
  __hip_bfloat16* W2b = (__hip_bfloat16*)alloc(128 * 64 * 2);

  hipMemsetAsync(cnt, 0, (size_t)N * 4, stream);
  hipMemsetAsync(hs + (size_t)N * 256, 0, 256 * 2, stream);   // dummy zero row

  const int PREP_TOT = 512 * 192 + 64 * 128 + 128 * 64 + 512;
  k_prep<<<(PREP_TOT + 255) / 256, 256, 0, stream>>>(Wih, Whh, bih, bhh, fc1W, fc2W, Wcat, bias, W1b, W2b);
  k_count<<<(E + 255) / 256, 256, 0, stream>>>(ei + E, cnt, E);
  k_adj_init<<<(padE + 1023) / 1024, 1024, 0, stream>>>(adj, N, padE);
  k_scan<<<1, 1024, 0, stream>>>(cnt, row_ptr, cursor, dinv, N);
  k_transform<<<(N * T_STEPS) / 8, 256, 0, stream>>>(x, gcnW, dinv, hs);
  k_fill<<<(E + 255) / 256, 256, 0, stream>>>(ei, cursor, adj, E);
  k_gather_conv<<<N / 4, 256, 0, stream>>>(row_ptr, adj, dinv, hs, gcnb, convW, convb, seq, N);
  k_lstm_head<<<N / 16, 512, 0, stream>>>(seq, Wcat, bias, W1b, fc1b, W2b, fc2b, (float*)d_out, N);
}

// Round 8
// 287.946 us; speedup vs baseline: 2.7483x; 1.1677x over previous
//
#include <hip/hip_runtime.h>
#include <hip/hip_bf16.h>

#define T_STEPS 8
#define F_IN    128
#define H_GCN   32
#define H_CONV  64
#define H_LSTM  128

typedef __bf16 bf16x8 __attribute__((ext_vector_type(8)));
typedef float  f32x4  __attribute__((ext_vector_type(4)));
typedef unsigned short ushort8v __attribute__((ext_vector_type(8)));

__device__ __forceinline__ float sigm(float x)   { return 1.f / (1.f + __expf(-x)); }
__device__ __forceinline__ float tanh_f(float x) { return 1.f - 2.f / (__expf(2.f * x) + 1.f); }

__device__ __forceinline__ float ubf(unsigned short u) {
  union { unsigned int i; float f; } v; v.i = ((unsigned int)u) << 16; return v.f;
}
__device__ __forceinline__ unsigned short bfb(float f) {
  __hip_bfloat16 b = __float2bfloat16(f);
  return __builtin_bit_cast(unsigned short, b);
}

__device__ __forceinline__ bf16x8 load_bf8(const __hip_bfloat16* p) {
  int4 v = *reinterpret_cast<const int4*>(p);
  return __builtin_bit_cast(bf16x8, v);
}

// ---------------- K1: hs[r][o] = (x[r][:] @ gcn_W[:,o]) * dinv[r>>3], bf16 ----------------
__global__ __launch_bounds__(256) void k_transform(const float* __restrict__ x,
                                                   const float* __restrict__ W,
                                                   const float* __restrict__ dinv,
                                                   __hip_bfloat16* __restrict__ hs)
{
  __shared__ float Ws[F_IN * H_GCN];
  __shared__ float xs[8][F_IN];
  int tid = threadIdx.x;
  for (int i = tid; i < F_IN * H_GCN; i += 256) Ws[i] = W[i];
  long r0 = (long)blockIdx.x * 8;
  int idx = tid * 4;
  float4 xv = *reinterpret_cast<const float4*>(x + r0 * F_IN + idx);
  int rl = idx >> 7, c0 = idx & 127;
  xs[rl][c0] = xv.x; xs[rl][c0 + 1] = xv.y; xs[rl][c0 + 2] = xv.z; xs[rl][c0 + 3] = xv.w;
  __syncthreads();
  int rr = tid >> 5, o = tid & 31;
  float acc = 0.f;
  #pragma unroll 8
  for (int f = 0; f < F_IN; f += 4) {
    float4 x4 = *reinterpret_cast<const float4*>(&xs[rr][f]);
    acc = fmaf(x4.x, Ws[(f + 0) * H_GCN + o], acc);
    acc = fmaf(x4.y, Ws[(f + 1) * H_GCN + o], acc);
    acc = fmaf(x4.z, Ws[(f + 2) * H_GCN + o], acc);
    acc = fmaf(x4.w, Ws[(f + 3) * H_GCN + o], acc);
  }
  long r = r0 + rr;
  hs[r * H_GCN + o] = __float2bfloat16(acc * dinv[r >> 3]);
}

// ---------------- K2: in-degree count ----------------
__global__ void k_count(const int* __restrict__ col, int* __restrict__ cnt, int E)
{
  int i = blockIdx.x * 256 + threadIdx.x;
  if (i < E) atomicAdd(&cnt[col[i]], 1);
}

// ---------------- K2b: fill padded adjacency with dummy node N ----------------
__global__ void k_adj_init(int* __restrict__ adj, int N, int padE)
{
  int i = blockIdx.x * 1024 + threadIdx.x;
  if (i < padE) adj[i] = N;
}

// ---------------- K3: scan over counts padded to x16 -> row_ptr, cursor, dinv ----------------
__global__ __launch_bounds__(1024) void k_scan(const int* __restrict__ cnt,
                                               int* __restrict__ row_ptr,
                                               int* __restrict__ cursor,
                                               float* __restrict__ dinv, int N)
{
  __shared__ int s[1024];
  int tid = threadIdx.x;
  const int CH = (N + 1023) >> 10;
  int i0 = tid * CH;
  int sum = 0;
  for (int j = 0; j < CH; ++j) {
    int i = i0 + j;
    if (i < N) sum += (cnt[i] + 15) & ~15;
  }
  s[tid] = sum;
  __syncthreads();
  #pragma unroll
  for (int off = 1; off < 1024; off <<= 1) {
    int t = (tid >= off) ? s[tid - off] : 0;
    __syncthreads();
    s[tid] += t;
    __syncthreads();
  }
  int run = (tid > 0) ? s[tid - 1] : 0;
  for (int j = 0; j < CH; ++j) {
    int i = i0 + j;
    if (i < N) {
      int v = cnt[i];
      cursor[i] = run;
      row_ptr[i] = run;
      dinv[i] = rsqrtf((float)v + 1.0f);
      run += (v + 15) & ~15;
      if (i == N - 1) row_ptr[N] = run;
    }
  }
}

// ---------------- K4: fill adjacency ----------------
__global__ void k_fill(const int* __restrict__ ei, int* __restrict__ cursor,
                       int* __restrict__ adj, int E)
{
  int e = blockIdx.x * 256 + threadIdx.x;
  if (e < E) {
    int r = ei[e], c = ei[E + e];
    int pos = atomicAdd(&cursor[c], 1);
    adj[pos] = r;
  }
}

// ---------------- K5a: pure gather: g[n] = relu((hs[n] + sum hs[nbr]) * dn + b) ----------------
// Wave per node. No LDS, no barriers. Adjacency padded to x16 -> one branch-free
// 16-deep batch covers the average node in a single latency exposure.
__global__ __launch_bounds__(256) void k_gather(
    const int* __restrict__ row_ptr, const int* __restrict__ adj,
    const float* __restrict__ dinv, const __hip_bfloat16* __restrict__ hs,
    const float* __restrict__ gcnb,
    __hip_bfloat16* __restrict__ g, int N)
{
  int tid  = threadIdx.x;
  int wave = tid >> 6;
  int lane = tid & 63;

  int n = blockIdx.x * 4 + wave;
  int start = row_ptr[n], end = row_ptr[n + 1];
  float dn = dinv[n];

  const __hip_bfloat16* hl = hs + lane * 4;
  float acc0, acc1, acc2, acc3;
  {
    ushort4 hv = *reinterpret_cast<const ushort4*>(hl + (size_t)n * 256);
    acc0 = ubf(hv.x); acc1 = ubf(hv.y); acc2 = ubf(hv.z); acc3 = ubf(hv.w);
  }

  for (int base = start; base < end; base += 16) {
    int s0 = adj[base + 0],  s1 = adj[base + 1],  s2 = adj[base + 2],  s3 = adj[base + 3];
    int s4 = adj[base + 4],  s5 = adj[base + 5],  s6 = adj[base + 6],  s7 = adj[base + 7];
    int s8 = adj[base + 8],  s9 = adj[base + 9],  sa = adj[base + 10], sb = adj[base + 11];
    int sc = adj[base + 12], sd = adj[base + 13], se = adj[base + 14], sf = adj[base + 15];
    ushort4 r0 = *reinterpret_cast<const ushort4*>(hl + (size_t)s0 * 256);
    ushort4 r1 = *reinterpret_cast<const ushort4*>(hl + (size_t)s1 * 256);
    ushort4 r2 = *reinterpret_cast<const ushort4*>(hl + (size_t)s2 * 256);
    ushort4 r3 = *reinterpret_cast<const ushort4*>(hl + (size_t)s3 * 256);
    ushort4 r4 = *reinterpret_cast<const ushort4*>(hl + (size_t)s4 * 256);
    ushort4 r5 = *reinterpret_cast<const ushort4*>(hl + (size_t)s5 * 256);
    ushort4 r6 = *reinterpret_cast<const ushort4*>(hl + (size_t)s6 * 256);
    ushort4 r7 = *reinterpret_cast<const ushort4*>(hl + (size_t)s7 * 256);
    ushort4 r8 = *reinterpret_cast<const ushort4*>(hl + (size_t)s8 * 256);
    ushort4 r9 = *reinterpret_cast<const ushort4*>(hl + (size_t)s9 * 256);
    ushort4 ra = *reinterpret_cast<const ushort4*>(hl + (size_t)sa * 256);
    ushort4 rb = *reinterpret_cast<const ushort4*>(hl + (size_t)sb * 256);
    ushort4 rc = *reinterpret_cast<const ushort4*>(hl + (size_t)sc * 256);
    ushort4 rd = *reinterpret_cast<const ushort4*>(hl + (size_t)sd * 256);
    ushort4 re = *reinterpret_cast<const ushort4*>(hl + (size_t)se * 256);
    ushort4 rf = *reinterpret_cast<const ushort4*>(hl + (size_t)sf * 256);
    acc0 += ((ubf(r0.x) + ubf(r1.x)) + (ubf(r2.x) + ubf(r3.x))) + ((ubf(r4.x) + ubf(r5.x)) + (ubf(r6.x) + ubf(r7.x)))
          + ((ubf(r8.x) + ubf(r9.x)) + (ubf(ra.x) + ubf(rb.x))) + ((ubf(rc.x) + ubf(rd.x)) + (ubf(re.x) + ubf(rf.x)));
    acc1 += ((ubf(r0.y) + ubf(r1.y)) + (ubf(r2.y) + ubf(r3.y))) + ((ubf(r4.y) + ubf(r5.y)) + (ubf(r6.y) + ubf(r7.y)))
          + ((ubf(r8.y) + ubf(r9.y)) + (ubf(ra.y) + ubf(rb.y))) + ((ubf(rc.y) + ubf(rd.y)) + (ubf(re.y) + ubf(rf.y)));
    acc2 += ((ubf(r0.z) + ubf(r1.z)) + (ubf(r2.z) + ubf(r3.z))) + ((ubf(r4.z) + ubf(r5.z)) + (ubf(r6.z) + ubf(r7.z)))
          + ((ubf(r8.z) + ubf(r9.z)) + (ubf(ra.z) + ubf(rb.z))) + ((ubf(rc.z) + ubf(rd.z)) + (ubf(re.z) + ubf(rf.z)));
    acc3 += ((ubf(r0.w) + ubf(r1.w)) + (ubf(r2.w) + ubf(r3.w))) + ((ubf(r4.w) + ubf(r5.w)) + (ubf(r6.w) + ubf(r7.w)))
          + ((ubf(r8.w) + ubf(r9.w)) + (ubf(ra.w) + ubf(rb.w))) + ((ubf(rc.w) + ubf(rd.w)) + (ubf(re.w) + ubf(rf.w)));
  }

  int ci0 = (lane * 4) & 31;
  ushort4 o;
  o.x = bfb(fmaxf(fmaf(acc0, dn, gcnb[ci0 + 0]), 0.f));
  o.y = bfb(fmaxf(fmaf(acc1, dn, gcnb[ci0 + 1]), 0.f));
  o.z = bfb(fmaxf(fmaf(acc2, dn, gcnb[ci0 + 2]), 0.f));
  o.w = bfb(fmaxf(fmaf(acc3, dn, gcnb[ci0 + 3]), 0.f));
  *reinterpret_cast<ushort4*>(g + (size_t)n * 256 + lane * 4) = o;
}

// ---------------- K5b: conv as MFMA GEMM ----------------
// im2col: A[row=(node,t)][k=ci*2+kk] = g[node][t+kk][ci];  B[k][co] = convW[co*64+k].
// Block: 256 thr = 4 waves, 8 nodes; wave w owns nodes {2w, 2w+1} = 14 rows + 2 pad.
// Per wave: 2 ds_read_b128 + 8 MFMA replace ~900 scalar LDS reads of the old kernel.
__global__ __launch_bounds__(256) void k_conv(
    const __hip_bfloat16* __restrict__ g,    // [N][256]
    const __hip_bfloat16* __restrict__ Wcb,  // [64][64] bf16 cast of convW
    const float* __restrict__ bc,
    __hip_bfloat16* __restrict__ seq, int N)
{
  __shared__ __hip_bfloat16 A[4][16][72];    // 144B rows, 16B-aligned
  int tid  = threadIdx.x;
  int wave = tid >> 6;
  int lane = tid & 63;
  int l15  = lane & 15;
  int lhi  = lane >> 4;

  // zero the 2 pad rows of each wave tile (rows 14,15)
  if (tid < 144) {
    int w = tid / 36, q = tid % 36;
    int row = 14 + q / 18, cc = (q % 18) * 4;
    *reinterpret_cast<uint2*>(&A[w][row][cc]) = make_uint2(0u, 0u);
  }

  // stage 8 nodes of g, scattering into im2col positions
  {
    int f0 = tid * 8;                               // 8 consecutive g elements
    ushort8v v = *reinterpret_cast<const ushort8v*>(g + (size_t)blockIdx.x * 2048 + f0);
    int n_local = f0 >> 8;
    int rem     = f0 & 255;
    int t_row   = rem >> 5;                          // all 8 elems share t_row
    int ci0     = rem & 31;
    int w       = n_local >> 1;
    int rbase   = (n_local & 1) * 7;
    #pragma unroll
    for (int e = 0; e < 8; ++e) {
      unsigned short u = v[e];
      int k0 = (ci0 + e) * 2;
      if (t_row <= 6)
        *reinterpret_cast<unsigned short*>(&A[w][rbase + t_row][k0]) = u;       // kk=0
      if (t_row >= 1)
        *reinterpret_cast<unsigned short*>(&A[w][rbase + t_row - 1][k0 + 1]) = u; // kk=1
    }
  }
  __syncthreads();

  // B fragments (L2-resident, 8 loads)
  bf16x8 bfr[2][4];
  #pragma unroll
  for (int ks = 0; ks < 2; ++ks)
    #pragma unroll
    for (int cg = 0; cg < 4; ++cg)
      bfr[ks][cg] = load_bf8(Wcb + (cg * 16 + l15) * 64 + ks * 32 + lhi * 8);

  f32x4 acc[4];
  #pragma unroll
  for (int cg = 0; cg < 4; ++cg) acc[cg] = (f32x4){0.f, 0.f, 0.f, 0.f};

  #pragma unroll
  for (int ks = 0; ks < 2; ++ks) {
    bf16x8 a = load_bf8(&A[wave][l15][ks * 32 + lhi * 8]);
    #pragma unroll
    for (int cg = 0; cg < 4; ++cg)
      acc[cg] = __builtin_amdgcn_mfma_f32_16x16x32_bf16(a, bfr[ks][cg], acc[cg], 0, 0, 0);
  }

  long n64 = (long)N * 64;
  #pragma unroll
  for (int r = 0; r < 4; ++r) {
    int rr = lhi * 4 + r;
    if (rr < 14) {
      int hi = rr >= 7 ? 1 : 0;
      int nl = wave * 2 + hi;
      int t  = rr - 7 * hi;
      long n = (long)blockIdx.x * 8 + nl;
      #pragma unroll
      for (int cg = 0; cg < 4; ++cg) {
        int co = cg * 16 + l15;
        seq[(long)t * n64 + n * 64 + co] = __float2bfloat16(fmaxf(acc[cg][r] + bc[co], 0.f));
      }
    }
  }
}

// ---------------- K6: pack bf16 weights (parallel elementwise) ----------------
__global__ __launch_bounds__(256) void k_prep(const float* __restrict__ Wih, const float* __restrict__ Whh,
                       const float* __restrict__ bih, const float* __restrict__ bhh,
                       const float* __restrict__ fc1W, const float* __restrict__ fc2W,
                       const float* __restrict__ convW,
                       __hip_bfloat16* __restrict__ Wcat, float* __restrict__ bias,
                       __hip_bfloat16* __restrict__ W1b, __hip_bfloat16* __restrict__ W2b,
                       __hip_bfloat16* __restrict__ Wcb)
{
  int i = blockIdx.x * 256 + threadIdx.x;
  if (i < 512 * 192) {
    int q = i / 192, k = i - q * 192;
    float v = (k < 64) ? Wih[q * 64 + k] : Whh[q * 128 + (k - 64)];
    Wcat[i] = __float2bfloat16(v);
  } else if (i < 512 * 192 + 64 * 128) {
    int j = i - 512 * 192;
    W1b[j] = __float2bfloat16(fc1W[j]);
  } else if (i < 512 * 192 + 64 * 128 + 128 * 64) {
    int j = i - 512 * 192 - 64 * 128;
    W2b[j] = __float2bfloat16(fc2W[j]);
  } else if (i < 512 * 192 + 64 * 128 + 128 * 64 + 64 * 64) {
    int j = i - 512 * 192 - 64 * 128 - 128 * 64;
    Wcb[j] = __float2bfloat16(convW[j]);
  } else if (i < 512 * 192 + 64 * 128 + 128 * 64 + 64 * 64 + 512) {
    int j = i - 512 * 192 - 64 * 128 - 128 * 64 - 64 * 64;
    bias[j] = bih[j] + bhh[j];
  }
}

// ---------------- K7: fused 7-step LSTM + head ----------------
__global__ __launch_bounds__(512, 2) void k_lstm_head(
    const __hip_bfloat16* __restrict__ seq,   // [7][N][64]
    const __hip_bfloat16* __restrict__ Wcat,  // [512][192]
    const float* __restrict__ bias,           // [512]
    const __hip_bfloat16* __restrict__ W1b,   // [64][128]
    const float* __restrict__ fc1b,
    const __hip_bfloat16* __restrict__ W2b,   // [128][64]
    const float* __restrict__ fc2b,
    float* __restrict__ out, int N)
{
  __shared__ __hip_bfloat16 h_lds[2][16][136];
  __shared__ __hip_bfloat16 s1_lds[16][72];
  int tid  = threadIdx.x;
  int wave = tid >> 6;
  int lane = tid & 63;
  int l15  = lane & 15;
  int lhi  = lane >> 4;
  long n0  = (long)blockIdx.x * 16;
  int hc   = wave * 16 + l15;

  bf16x8 bw[6][4];
  #pragma unroll
  for (int ks = 0; ks < 6; ++ks)
    #pragma unroll
    for (int gg = 0; gg < 4; ++gg)
      bw[ks][gg] = load_bf8(Wcat + (size_t)(gg * 128 + hc) * 192 + ks * 32 + lhi * 8);

  float bi = bias[hc], bff = bias[128 + hc], bg = bias[256 + hc], bo = bias[384 + hc];
  float c[4] = {0.f, 0.f, 0.f, 0.f};

  const __hip_bfloat16* sp = seq + (n0 + l15) * 64 + lhi * 8;
  size_t tstr = (size_t)N * 64;
  bf16x8 ax0 = load_bf8(sp);
  bf16x8 ax1 = load_bf8(sp + 32);

  for (int t = 0; t < 7; ++t) {
    bf16x8 nx0, nx1;
    if (t < 6) {
      nx0 = load_bf8(sp + (size_t)(t + 1) * tstr);
      nx1 = load_bf8(sp + (size_t)(t + 1) * tstr + 32);
    }
    f32x4 acc[4];
    #pragma unroll
    for (int gg = 0; gg < 4; ++gg) acc[gg] = (f32x4){0.f, 0.f, 0.f, 0.f};

    #pragma unroll
    for (int gg = 0; gg < 4; ++gg)
      acc[gg] = __builtin_amdgcn_mfma_f32_16x16x32_bf16(ax0, bw[0][gg], acc[gg], 0, 0, 0);
    #pragma unroll
    for (int gg = 0; gg < 4; ++gg)
      acc[gg] = __builtin_amdgcn_mfma_f32_16x16x32_bf16(ax1, bw[1][gg], acc[gg], 0, 0, 0);

    if (t > 0) {
      const __hip_bfloat16* hb = &h_lds[(t + 1) & 1][0][0];
      #pragma unroll
      for (int ks = 2; ks < 6; ++ks) {
        bf16x8 a = load_bf8(hb + l15 * 136 + (ks - 2) * 32 + lhi * 8);
        #pragma unroll
        for (int gg = 0; gg < 4; ++gg)
          acc[gg] = __builtin_amdgcn_mfma_f32_16x16x32_bf16(a, bw[ks][gg], acc[gg], 0, 0, 0);
      }
    }

    __hip_bfloat16* hw = &h_lds[t & 1][0][0];
    #pragma unroll
    for (int r = 0; r < 4; ++r) {
      float zi = acc[0][r] + bi;
      float zf = acc[1][r] + bff;
      float zg = acc[2][r] + bg;
      float zo = acc[3][r] + bo;
      float cn = sigm(zf) * c[r] + sigm(zi) * tanh_f(zg);
      c[r] = cn;
      hw[(lhi * 4 + r) * 136 + hc] = __float2bfloat16(sigm(zo) * tanh_f(cn));
    }
    __syncthreads();

    ax0 = nx0; ax1 = nx1;
  }

  if (wave < 4) {
    int col1 = wave * 16 + l15;
    f32x4 acc1 = (f32x4){0.f, 0.f, 0.f, 0.f};
    #pragma unroll
    for (int ks = 0; ks < 4; ++ks) {
      int kb = ks * 32 + lhi * 8;
      bf16x8 a = load_bf8(&h_lds[0][l15][kb]);
      bf16x8 b = load_bf8(W1b + col1 * 128 + kb);
      acc1 = __builtin_amdgcn_mfma_f32_16x16x32_bf16(a, b, acc1, 0, 0, 0);
    }
    float b1 = fc1b[col1];
    #pragma unroll
    for (int r = 0; r < 4; ++r)
      s1_lds[lhi * 4 + r][col1] = __float2bfloat16(fmaxf(acc1[r] + b1, 0.f));
  }
  __syncthreads();

  {
    int c2 = wave * 16 + l15;
    f32x4 acc2 = (f32x4){0.f, 0.f, 0.f, 0.f};
    #pragma unroll
    for (int ks = 0; ks < 2; ++ks) {
      int kb = ks * 32 + lhi * 8;
      bf16x8 a = load_bf8(&s1_lds[l15][kb]);
      bf16x8 b = load_bf8(W2b + c2 * 64 + kb);
      acc2 = __builtin_amdgcn_mfma_f32_16x16x32_bf16(a, b, acc2, 0, 0, 0);
    }
    float b2 = fc2b[c2];
    #pragma unroll
    for (int r = 0; r < 4; ++r)
      out[(n0 + lhi * 4 + r) * 128 + c2] = sigm(acc2[r] + b2);
  }
}

extern "C" void kernel_launch(void* const* d_in, const int* in_sizes, int n_in,
                              void* d_out, int out_size, void* d_ws, size_t ws_size,
                              hipStream_t stream)
{
  const float* x     = (const float*)d_in[0];
  const int*   ei    = (const int*)d_in[1];
  const float* gcnW  = (const float*)d_in[2];
  const float* gcnb  = (const float*)d_in[3];
  const float* convW = (const float*)d_in[4];
  const float* convb = (const float*)d_in[5];
  const float* Wih   = (const float*)d_in[6];
  const float* Whh   = (const float*)d_in[7];
  const float* bih   = (const float*)d_in[8];
  const float* bhh   = (const float*)d_in[9];
  const float* fc1W  = (const float*)d_in[10];
  const float* fc1b  = (const float*)d_in[11];
  const float* fc2W  = (const float*)d_in[12];
  const float* fc2b  = (const float*)d_in[13];

  const int N = in_sizes[0] / (T_STEPS * F_IN);
  const int E = in_sizes[1] / 2;
  const int padE = E + 16 * N;

  char* ws = (char*)d_ws;
  size_t off = 0;
  auto alloc = [&](size_t bytes) {
    void* p = ws + off;
    off = (off + bytes + 255) & ~(size_t)255;
    return p;
  };
  __hip_bfloat16* hs  = (__hip_bfloat16*)alloc((size_t)(N + 1) * 256 * 2); // [N+1][256], row N zeros
  __hip_bfloat16* g   = (__hip_bfloat16*)alloc((size_t)N * 256 * 2);       // gathered+relu'd GCN out
  __hip_bfloat16* seq = (__hip_bfloat16*)alloc((size_t)7 * N * 64 * 2);    // [7][N][64]
  int* cnt     = (int*)alloc((size_t)N * 4);
  int* row_ptr = (int*)alloc((size_t)(N + 1) * 4);
  int* cursor  = (int*)alloc((size_t)N * 4);
  float* dinv  = (float*)alloc((size_t)N * 4);
  int* adj     = (int*)alloc((size_t)padE * 4);
  __hip_bfloat16* Wcat = (__hip_bfloat16*)alloc(512 * 192 * 2);
  float* bias = (float*)alloc(512 * 4);
  __hip_bfloat16* W1b = (__hip_bfloat16*)alloc(64 * 128 * 2);
  __hip_bfloat16* W2b = (__hip_bfloat16*)alloc(128 * 64 * 2);
  __hip_bfloat16* Wcb = (__hip_bfloat16*)alloc(64 * 64 * 2);

  hipMemsetAsync(cnt, 0, (size_t)N * 4, stream);
  hipMemsetAsync(hs + (size_t)N * 256, 0, 256 * 2, stream);   // dummy zero row

  const int PREP_TOT = 512 * 192 + 64 * 128 + 128 * 64 + 64 * 64 + 512;
  k_prep<<<(PREP_TOT + 255) / 256, 256, 0, stream>>>(Wih, Whh, bih, bhh, fc1W, fc2W, convW,
                                                     Wcat, bias, W1b, W2b, Wcb);
  k_count<<<(E + 255) / 256, 256, 0, stream>>>(ei + E, cnt, E);
  k_adj_init<<<(padE + 1023) / 1024, 1024, 0, stream>>>(adj, N, padE);
  k_scan<<<1, 1024, 0, stream>>>(cnt, row_ptr, cursor, dinv, N);
  k_transform<<<(N * T_STEPS) / 8, 256, 0, stream>>>(x, gcnW, dinv, hs);
  k_fill<<<(E + 255) / 256, 256, 0, stream>>>(ei, cursor, adj, E);
  k_gather<<<N / 4, 256, 0, stream>>>(row_ptr, adj, dinv, hs, gcnb, g, N);
  k_conv<<<N / 8, 256, 0, stream>>>(g, Wcb, convb, seq, N);
  k_lstm_head<<<N / 16, 512, 0, stream>>>(seq, Wcat, bias, W1b, fc1b, W2b, fc2b, (float*)d_out, N);
}